// Round 4
// baseline (2001.963 us; speedup 1.0000x reference)
//
#include <hip/hip_runtime.h>
#include <math.h>

#define GGRP 8
#define NPTS 8192
#define NG   1024      // points per group
#define BB   4
#define FF   64
#define CH   11
#define KF   192       // feature dim F*3
#define NGB  32        // G*B
#define KNN  16

// ws offsets in FLOATS
#define OFF_ORD_E  0        // 8192 int
#define OFF_ORD_A  8192     // 8192 int
#define OFF_BG_E   16384    // 8192 int
#define OFF_BG_A   24576    // 8192 int
#define OFF_MEAN_E 32768    // 96 f
#define OFF_MEAN_A 32896    // 96 f
#define OFF_STD_E  33024    // 2048 f
#define OFF_STD_A  35072    // 2048 f
#define OFF_MEANP  37888    // 2*32*64*3 = 12288 f
#define OFF_PART   50176    // up to 8192*3 f
#define OFF_NORMP  74752    // 6*32*3*1024 = 589824 f
#define OFF_NORMS  664576   // 6*32*1024 = 196608 f
#define OFF_MAT    1048576
#define MATSZ      6291456  // 32*192*1024 floats per matrix-set
#define OFF_BMAT   38797312 // OFF_MAT + 6*MATSZ ; bf16 mats (fast) / D (fallback)
#define BMAT_FLOATS 18874368
#define FAST_END   57671680 // OFF_BMAT + BMAT_FLOATS
#define OFF_D      38797312 // fallback D region
// matrix order: 0 PE, 1 PA, 2 VE, 3 VA, 4 NPE, 5 NPA

typedef short bf16x8 __attribute__((ext_vector_type(8)));
typedef float f32x4 __attribute__((ext_vector_type(4)));

__global__ void k_bg(const float* __restrict__ ex, const float* __restrict__ ac, float* ws) {
    int n = blockIdx.x * blockDim.x + threadIdx.x;
    if (n >= NPTS) return;
    int* bg_e = (int*)ws + OFF_BG_E;
    int* bg_a = (int*)ws + OFF_BG_A;
    const float* pe = ex + (size_t)n * CH + 3;
    const float* pa = ac + (size_t)n * CH + 3;
    float m = -1e30f; int a = 0;
    for (int c = 0; c < GGRP; c++) { float v = pe[c]; if (v > m) { m = v; a = c; } }
    bg_e[n] = a;
    m = -1e30f; a = 0;
    for (int c = 0; c < GGRP; c++) { float v = pa[c]; if (v > m) { m = v; a = c; } }
    bg_a[n] = a;
}

// stable counting-compaction: 16 waves, wave w<8 -> expected group w, w>=8 -> actual group w-8
__global__ void k_order(float* ws) {
    int tid = threadIdx.x;
    int w = tid >> 6, lane = tid & 63;
    const int* bg = (const int*)ws + ((w < 8) ? OFF_BG_E : OFF_BG_A);
    int* ord = (int*)ws + ((w < 8) ? OFF_ORD_E : OFF_ORD_A);
    int grp = w & 7;
    __shared__ int cnts[16];
    int cnt = 0;
    for (int base = 0; base < NPTS; base += 64) {
        int v = bg[base + lane];
        unsigned long long m = __ballot(v == grp);
        cnt += __popcll(m);
    }
    if (lane == 0) cnts[w] = cnt;
    __syncthreads();
    int pos = 0;
    for (int g2 = 0; g2 < grp; g2++) pos += cnts[(w & 8) | g2];
    for (int base = 0; base < NPTS; base += 64) {
        int v = bg[base + lane];
        unsigned long long m = __ballot(v == grp);
        int pre = __popcll(m & ((1ull << lane) - 1ull));
        if (v == grp) { int slot = pos + pre; if (slot < NPTS) ord[slot] = base + lane; }
        pos += __popcll(m);
    }
}

// build PE_T / PA_T : layout [gb][k=f*3+c][i] ; also per-(gb,f) coord-sum partials
__global__ void k_gather(const float* __restrict__ ex, const float* __restrict__ ac, float* ws) {
    int f = blockIdx.x, gb = blockIdx.y;
    int g = gb >> 2, b = gb & 3;
    const int* ord_e = (const int*)ws + OFF_ORD_E;
    const int* ord_a = (const int*)ws + OFF_ORD_A;
    float* PE = ws + OFF_MAT;
    float* PA = ws + OFF_MAT + (size_t)1 * MATSZ;
    size_t mbase = ((size_t)gb * KF + f * 3) * NG;
    size_t sbase = ((size_t)(b * FF + f)) * NPTS;
    float sums[6] = {0, 0, 0, 0, 0, 0};
    for (int i = threadIdx.x; i < NG; i += blockDim.x) {
        int ne = ord_e[g * NG + i];
        const float* p = ex + (sbase + ne) * CH;
        float e0 = p[0], e1 = p[1], e2 = p[2];
        PE[mbase + i] = e0; PE[mbase + NG + i] = e1; PE[mbase + 2 * NG + i] = e2;
        sums[0] += e0; sums[1] += e1; sums[2] += e2;
        int na = ord_a[g * NG + i];
        const float* q = ac + (sbase + na) * CH;
        float a0 = q[0], a1 = q[1], a2 = q[2];
        PA[mbase + i] = a0; PA[mbase + NG + i] = a1; PA[mbase + 2 * NG + i] = a2;
        sums[3] += a0; sums[4] += a1; sums[5] += a2;
    }
    __shared__ float red[256];
    for (int c = 0; c < 6; c++) {
        red[threadIdx.x] = sums[c]; __syncthreads();
        for (int off = 128; off; off >>= 1) { if (threadIdx.x < off) red[threadIdx.x] += red[threadIdx.x + off]; __syncthreads(); }
        if (threadIdx.x == 0) {
            int side = c / 3;
            ws[OFF_MEANP + ((size_t)(side * NGB + gb) * FF + f) * 3 + (c % 3)] = red[0];
        }
        __syncthreads();
    }
}

__global__ void k_meanfin(float* ws) {
    int gb = blockIdx.x, side = blockIdx.y;
    int lane = threadIdx.x;
    const float* mp = ws + OFF_MEANP + ((size_t)(side * NGB + gb) * FF) * 3;
    float s0 = mp[lane * 3], s1 = mp[lane * 3 + 1], s2 = mp[lane * 3 + 2];
#pragma unroll
    for (int off = 32; off; off >>= 1) {
        s0 += __shfl_xor(s0, off); s1 += __shfl_xor(s1, off); s2 += __shfl_xor(s2, off);
    }
    if (lane == 0) {
        float* m = ws + (side ? OFF_MEAN_A : OFF_MEAN_E) + gb * 3;
        m[0] = s0 / 65536.0f; m[1] = s1 / 65536.0f; m[2] = s2 / 65536.0f;
    }
}

// std over (n,3) of centered data, ddof=1, WITH its own mean subtraction (two-sum form)
__global__ void k_std(float* ws) {
    int gb = blockIdx.x, f = blockIdx.y, side = blockIdx.z;
    const float* M = ws + OFF_MAT + (size_t)side * MATSZ + ((size_t)gb * KF + f * 3) * NG;
    const float* mean = ws + (side ? OFF_MEAN_A : OFF_MEAN_E) + gb * 3;
    float m0 = mean[0], m1 = mean[1], m2 = mean[2];
    float s2 = 0, s1 = 0;
    for (int idx = threadIdx.x; idx < 3 * NG; idx += 128) {
        int c = idx >> 10;
        float mm = (c == 0) ? m0 : ((c == 1) ? m1 : m2);
        float v = M[idx] - mm;
        s1 += v; s2 += v * v;
    }
    __shared__ float redA[128], redB[128];
    redA[threadIdx.x] = s1; redB[threadIdx.x] = s2; __syncthreads();
    for (int off = 64; off; off >>= 1) {
        if (threadIdx.x < off) { redA[threadIdx.x] += redA[threadIdx.x + off]; redB[threadIdx.x] += redB[threadIdx.x + off]; }
        __syncthreads();
    }
    if (threadIdx.x == 0) {
        float su = redA[0], sq = redB[0];
        float var = (sq - su * su / 3072.0f) / 3071.0f;
        float* st = ws + (side ? OFF_STD_A : OFF_STD_E);
        st[gb * FF + f] = sqrtf(fmaxf(var, 0.0f));
    }
}

__global__ void k_derive(float* ws) {
    int k = blockIdx.x, gb = blockIdx.y;
    int f = k / 3, c = k % 3;
    for (int side = 0; side < 2; side++) {
        const float* P = ws + OFF_MAT + (size_t)side * MATSZ;
        float* V = ws + OFF_MAT + (size_t)(2 + side) * MATSZ;
        float* NP = ws + OFF_MAT + (size_t)(4 + side) * MATSZ;
        const float* mean = ws + (side ? OFF_MEAN_A : OFF_MEAN_E) + gb * 3;
        const float* st = ws + (side ? OFF_STD_A : OFF_STD_E) + gb * FF;
        float mm = mean[c];
        float rs = 1.0f / st[f];
        size_t base = ((size_t)gb * KF + k) * NG;
        for (int i = threadIdx.x; i < NG; i += 256) {
            float p = P[base + i];
            V[base + i] = f ? (p - P[base - 3 * NG + i]) : 0.0f;
            NP[base + i] = (p - mm) * rs;
        }
    }
}

// fallback-path norms (fp32 mats)
__global__ void k_norms(float* ws) {
    int mat = blockIdx.x, gb = blockIdx.y;
    const float* M = ws + OFF_MAT + (size_t)mat * MATSZ + (size_t)gb * KF * NG;
    float* nr = ws + OFF_NORMS + ((size_t)mat * NGB + gb) * NG;
    for (int i = threadIdx.x; i < NG; i += 256) {
        float s = 0;
        for (int k = 0; k < KF; k++) { float v = M[(size_t)k * NG + i]; s += v * v; }
        nr[i] = s;
    }
}

// transpose-convert fp32 [k][i] -> bf16 row-major [i][k] ; fold ||.||^2 partials
__global__ void k_tobf16(float* ws) {
    int x = blockIdx.x;            // 0..47: it = x&15, kt = x>>4
    int it = x & 15, kt = x >> 4;
    int gb = blockIdx.y, mat = blockIdx.z;
    const float* M = ws + OFF_MAT + (size_t)mat * MATSZ + (size_t)gb * KF * NG;
    unsigned short* out = (unsigned short*)(ws + OFF_BMAT) + ((size_t)mat * NGB + gb) * (size_t)(NG * KF);
    float* normp = ws + OFF_NORMP + ((size_t)(mat * NGB + gb) * 3 + kt) * NG;
    __shared__ float tile[64][65];
    int i0 = it * 64, k0 = kt * 64;
    int t = threadIdx.x;
    int ii = t & 63, kq = t >> 6;
#pragma unroll
    for (int rep = 0; rep < 16; rep++) {
        int kk = kq + rep * 4;
        tile[kk][ii] = M[(size_t)(k0 + kk) * NG + i0 + ii];
    }
    __syncthreads();
    int kk2 = t & 63, iq = t >> 6;
#pragma unroll
    for (int rep = 0; rep < 16; rep++) {
        int i2 = iq + rep * 4;
        float v = tile[kk2][i2];
        unsigned u = __builtin_bit_cast(unsigned, v);
        unsigned r = (u + 0x7fffu + ((u >> 16) & 1u)) >> 16;   // RNE bf16
        out[(size_t)(i0 + i2) * KF + k0 + kk2] = (unsigned short)r;
        float nsq = v * v;
#pragma unroll
        for (int off = 32; off; off >>= 1) nsq += __shfl_xor(nsq, off);
        if (kk2 == 0) normp[i0 + i2] = nsq;
    }
}

__global__ void k_normfin(float* ws) {
    int mat = blockIdx.x, gb = blockIdx.y;
    const float* np = ws + OFF_NORMP + (size_t)(mat * NGB + gb) * 3 * NG;
    float* nr = ws + OFF_NORMS + ((size_t)mat * NGB + gb) * NG;
    for (int i = threadIdx.x; i < NG; i += 256)
        nr[i] = np[i] + np[NG + i] + np[2 * NG + i];
}

// ---------------------------------------------------------------------------
// Fused distance-GEMM + per-row top-16 selection (no D materialization).
// NM=2: dg (mats 0,1) with dv carried (mats 2,3) -> part slots 0,2
// NM=1: dn (mats 4,5)                            -> part slot 1
// Block: 64 E-rows (panel) x 1024 A-cols, 4 waves (2 row-groups x 2 col-halves).
// Wave: 32 rows x 64 cols per 128-col tile. E-frags in registers; A staged in
// LDS (32KB, XOR-swizzled, global_load_lds). Selection on squared distances,
// running top-16 per row held one-entry-per-lane in each 16-lane group.
// ---------------------------------------------------------------------------
template<int NM>
__global__ __launch_bounds__(256) void k_fsel(float* ws) {
    int panel = blockIdx.x, gb = blockIdx.y;
    const int e0 = (NM == 2) ? 0 : 4;
    const int a0 = (NM == 2) ? 1 : 5;
    const unsigned short* bmat = (const unsigned short*)(ws + OFF_BMAT);
    const unsigned short* Eg0 = bmat + ((size_t)e0 * NGB + gb) * (size_t)(NG * KF);
    const unsigned short* Ag0 = bmat + ((size_t)a0 * NGB + gb) * (size_t)(NG * KF);
    const unsigned short* Eg1 = bmat + ((size_t)2 * NGB + gb) * (size_t)(NG * KF);
    const unsigned short* Ag1 = bmat + ((size_t)3 * NGB + gb) * (size_t)(NG * KF);
    const float* rn0 = ws + OFF_NORMS + ((size_t)e0 * NGB + gb) * NG;
    const float* cn0 = ws + OFF_NORMS + ((size_t)a0 * NGB + gb) * NG;
    const float* rn1 = ws + OFF_NORMS + ((size_t)2 * NGB + gb) * NG;
    const float* cn1 = ws + OFF_NORMS + ((size_t)3 * NGB + gb) * NG;

    __shared__ __align__(16) char sbuf[NM * 16384];
    __shared__ float fb[4];

    int tid = threadIdx.x, w = tid >> 6, lane = tid & 63;
    int wr = w >> 1, wc2 = w & 1;
    int l15 = lane & 15, lg = lane >> 4;
    int rowbase = panel * 64 + wr * 32;

    // E fragments in registers: [rf][ks] ; lane holds row (l15), k = ks*32+lg*8
    bf16x8 ef0[2][6], ef1[2][6];
#pragma unroll
    for (int rf = 0; rf < 2; rf++)
#pragma unroll
        for (int ks = 0; ks < 6; ks++) {
            size_t off = (size_t)(rowbase + rf * 16 + l15) * KF + ks * 32 + lg * 8;
            ef0[rf][ks] = *(const bf16x8*)(Eg0 + off);
            if (NM == 2) ef1[rf][ks] = *(const bf16x8*)(Eg1 + off);
        }
    // row norms per row-slot (C row = lg*4 + r within 16-row frag)
    float rnr0[2][4], rnr1[2][4];
#pragma unroll
    for (int rf = 0; rf < 2; rf++)
#pragma unroll
        for (int r = 0; r < 4; r++) {
            rnr0[rf][r] = rn0[rowbase + rf * 16 + lg * 4 + r];
            if (NM == 2) rnr1[rf][r] = rn1[rowbase + rf * 16 + lg * 4 + r];
            else rnr1[rf][r] = 0.0f;
        }

    // running top-16 squared distances (one entry per lane of 16-lane group)
    float Lg[2][4], Lv[2][4];

    for (int ct = 0; ct < 8; ct++) {
        f32x4 acc0[2][4], acc1[2][4];
#pragma unroll
        for (int rf = 0; rf < 2; rf++)
#pragma unroll
            for (int cf = 0; cf < 4; cf++) {
                acc0[rf][cf] = (f32x4){0.f, 0.f, 0.f, 0.f};
                if (NM == 2) acc1[rf][cf] = (f32x4){0.f, 0.f, 0.f, 0.f};
            }
        int cq = lane >> 3, kq = lane & 7;
#pragma unroll
        for (int kc = 0; kc < 3; kc++) {
            __syncthreads();
#pragma unroll
            for (int q = 0; q < 4; q++) {
                int c8 = w * 32 + q * 8 + cq;          // col within tile
                int kk = kq ^ (c8 & 7);                // pre-swizzled k-group
                __builtin_amdgcn_global_load_lds(
                    (const __attribute__((address_space(1))) void*)(Ag0 + (size_t)(ct * 128 + c8) * KF + kc * 64 + kk * 8),
                    (__attribute__((address_space(3))) void*)(sbuf + (size_t)(w * 32 + q * 8) * 128), 16, 0, 0);
                if (NM == 2)
                    __builtin_amdgcn_global_load_lds(
                        (const __attribute__((address_space(1))) void*)(Ag1 + (size_t)(ct * 128 + c8) * KF + kc * 64 + kk * 8),
                        (__attribute__((address_space(3))) void*)(sbuf + 16384 + (size_t)(w * 32 + q * 8) * 128), 16, 0, 0);
            }
            asm volatile("s_waitcnt vmcnt(0)" ::: "memory");
            __syncthreads();
#pragma unroll
            for (int ks2 = 0; ks2 < 2; ks2++) {
                const int ksg = kc * 2 + ks2;
                bf16x8 b0[4], b1[4];
#pragma unroll
                for (int cf = 0; cf < 4; cf++) {
                    int col = wc2 * 64 + cf * 16 + l15;
                    int kb = (ks2 * 64 + lg * 16) ^ ((col & 7) << 4);
                    b0[cf] = *(const bf16x8*)(sbuf + (size_t)col * 128 + kb);
                    if (NM == 2) b1[cf] = *(const bf16x8*)(sbuf + 16384 + (size_t)col * 128 + kb);
                }
#pragma unroll
                for (int rf = 0; rf < 2; rf++)
#pragma unroll
                    for (int cf = 0; cf < 4; cf++) {
                        acc0[rf][cf] = __builtin_amdgcn_mfma_f32_16x16x32_bf16(ef0[rf][ksg], b0[cf], acc0[rf][cf], 0, 0, 0);
                        if (NM == 2) acc1[rf][cf] = __builtin_amdgcn_mfma_f32_16x16x32_bf16(ef1[rf][ksg], b1[cf], acc1[rf][cf], 0, 0, 0);
                    }
            }
        }
        // --- selection epilogue for this 128-col tile (squared distances) ---
        float cn0v[4], cn1v[4];
#pragma unroll
        for (int cf = 0; cf < 4; cf++) {
            int colg = ct * 128 + wc2 * 64 + cf * 16 + l15;
            cn0v[cf] = cn0[colg];
            if (NM == 2) cn1v[cf] = cn1[colg];
            else cn1v[cf] = 0.0f;
        }
#pragma unroll
        for (int rf = 0; rf < 2; rf++)
#pragma unroll
            for (int r = 0; r < 4; r++) {
                float nv0[4], nv1[4];
#pragma unroll
                for (int cf = 0; cf < 4; cf++) {
                    nv0[cf] = rnr0[rf][r] + cn0v[cf] - 2.0f * acc0[rf][cf][r];
                    nv1[cf] = (NM == 2) ? (rnr1[rf][r] + cn1v[cf] - 2.0f * acc1[rf][cf][r]) : 0.0f;
                }
                if (ct == 0) {              // init list with frag 0's 16 values
                    Lg[rf][r] = nv0[0];
                    Lv[rf][r] = nv1[0];
                }
                float tau = Lg[rf][r];
#pragma unroll
                for (int off = 8; off; off >>= 1) tau = fmaxf(tau, __shfl_xor(tau, off));
#pragma unroll
                for (int cf = 0; cf < 4; cf++) {
                    if (ct == 0 && cf == 0) continue;      // already used as init
                    unsigned long long bal = __ballot(nv0[cf] < tau);
                    unsigned mask = (unsigned)(bal >> (lg * 16)) & 0xFFFFu;
                    while (mask) {
                        int s = __ffs(mask) - 1;
                        mask &= mask - 1;
                        float v = __shfl(nv0[cf], lg * 16 + s);
                        float vv = (NM == 2) ? __shfl(nv1[cf], lg * 16 + s) : 0.0f;
                        if (v < tau) {
                            float mv = Lg[rf][r]; int ml = lane;
#pragma unroll
                            for (int off = 8; off; off >>= 1) {
                                float ov = __shfl_xor(mv, off); int ol = __shfl_xor(ml, off);
                                if (ov > mv || (ov == mv && ol < ml)) { mv = ov; ml = ol; }
                            }
                            if (v < mv) {
                                if (lane == ml) { Lg[rf][r] = v; Lv[rf][r] = vv; }
                                float t2 = Lg[rf][r];
#pragma unroll
                                for (int off = 8; off; off >>= 1) t2 = fmaxf(t2, __shfl_xor(t2, off));
                                tau = t2;
                            } else tau = mv;
                        }
                    }
                }
            }
    }

    // --- merge the two col-half waves (wc2==1 -> LDS -> wc2==0 inserts) ---
    __syncthreads();
    float* mbuf = (float*)sbuf;
    if (wc2 == 1) {
#pragma unroll
        for (int rf = 0; rf < 2; rf++)
#pragma unroll
            for (int r = 0; r < 4; r++) {
                int rs = wr * 32 + rf * 16 + lg * 4 + r;
                mbuf[(rs * 16 + l15) * NM] = Lg[rf][r];
                if (NM == 2) mbuf[(rs * 16 + l15) * NM + 1] = Lv[rf][r];
            }
    }
    __syncthreads();
    float sA = 0, sB = 0;
    if (wc2 == 0) {
#pragma unroll
        for (int rf = 0; rf < 2; rf++)
#pragma unroll
            for (int r = 0; r < 4; r++) {
                int rs = wr * 32 + rf * 16 + lg * 4 + r;
                float v0 = mbuf[(rs * 16 + l15) * NM];
                float v1 = (NM == 2) ? mbuf[(rs * 16 + l15) * NM + 1] : 0.0f;
                float tau = Lg[rf][r];
#pragma unroll
                for (int off = 8; off; off >>= 1) tau = fmaxf(tau, __shfl_xor(tau, off));
                unsigned long long bal = __ballot(v0 < tau);
                unsigned mask = (unsigned)(bal >> (lg * 16)) & 0xFFFFu;
                while (mask) {
                    int s = __ffs(mask) - 1;
                    mask &= mask - 1;
                    float v = __shfl(v0, lg * 16 + s);
                    float vv = (NM == 2) ? __shfl(v1, lg * 16 + s) : 0.0f;
                    if (v < tau) {
                        float mv = Lg[rf][r]; int ml = lane;
#pragma unroll
                        for (int off = 8; off; off >>= 1) {
                            float ov = __shfl_xor(mv, off); int ol = __shfl_xor(ml, off);
                            if (ov > mv || (ov == mv && ol < ml)) { mv = ov; ml = ol; }
                        }
                        if (v < mv) {
                            if (lane == ml) { Lg[rf][r] = v; Lv[rf][r] = vv; }
                            float t2 = Lg[rf][r];
#pragma unroll
                            for (int off = 8; off; off >>= 1) t2 = fmaxf(t2, __shfl_xor(t2, off));
                            tau = t2;
                        } else tau = mv;
                    }
                }
                sA += sqrtf(fmaxf(Lg[rf][r], 1e-12f));
                if (NM == 2) sB += sqrtf(fmaxf(Lv[rf][r], 1e-12f));
            }
#pragma unroll
        for (int off = 32; off; off >>= 1) {
            sA += __shfl_xor(sA, off);
            if (NM == 2) sB += __shfl_xor(sB, off);
        }
        if (lane == 0) { fb[wr * 2] = sA; fb[wr * 2 + 1] = sB; }
    }
    __syncthreads();
    if (tid == 0) {
        float* part = ws + OFF_PART + (size_t)(gb * 16 + panel) * 3;
        if (NM == 2) { part[0] = fb[0] + fb[2]; part[2] = fb[1] + fb[3]; }
        else part[1] = fb[0] + fb[2];
    }
}

// fallback fp32 GEMM (small-ws path)
__global__ __launch_bounds__(256) void k_gemm(float* ws, int cs) {
    int bx = blockIdx.x, by = blockIdx.y;
    int bz = blockIdx.z; int gbl = bz / 3, m = bz % 3;
    int gb = cs + gbl;
    int eIdx = (m == 0) ? 0 : ((m == 1) ? 4 : 2);
    int aIdx = (m == 0) ? 1 : ((m == 1) ? 5 : 3);
    const float* E = ws + OFF_MAT + (size_t)eIdx * MATSZ + (size_t)gb * KF * NG;
    const float* A = ws + OFF_MAT + (size_t)aIdx * MATSZ + (size_t)gb * KF * NG;
    const float* rnE = ws + OFF_NORMS + ((size_t)eIdx * NGB + gb) * NG;
    const float* cnA = ws + OFF_NORMS + ((size_t)aIdx * NGB + gb) * NG;
    float* D = ws + OFF_D + ((size_t)gbl * 3 + m) * (size_t)(NG * NG);
    int i0 = by * 128, j0 = bx * 128;
    __shared__ float4 Et[8][32], At[8][32];
    int tx = threadIdx.x, ty = threadIdx.y;
    int tid = ty * 16 + tx;
    float acc[2][2][4][4] = {};
    for (int k0 = 0; k0 < KF; k0 += 8) {
        {
            int kk = tid >> 5, i4 = tid & 31;
            Et[kk][i4] = *(const float4*)&E[(size_t)(k0 + kk) * NG + i0 + i4 * 4];
            At[kk][i4] = *(const float4*)&A[(size_t)(k0 + kk) * NG + j0 + i4 * 4];
        }
        __syncthreads();
#pragma unroll
        for (int kk = 0; kk < 8; kk++) {
            float4 e0 = Et[kk][ty], e1 = Et[kk][16 + ty];
            float4 a0 = At[kk][tx], a1 = At[kk][16 + tx];
            float er[2][4] = {{e0.x, e0.y, e0.z, e0.w}, {e1.x, e1.y, e1.z, e1.w}};
            float ar[2][4] = {{a0.x, a0.y, a0.z, a0.w}, {a1.x, a1.y, a1.z, a1.w}};
#pragma unroll
            for (int p = 0; p < 2; p++)
#pragma unroll
                for (int q = 0; q < 2; q++)
#pragma unroll
                    for (int r = 0; r < 4; r++)
#pragma unroll
                        for (int cc = 0; cc < 4; cc++)
                            acc[p][q][r][cc] += er[p][r] * ar[q][cc];
        }
        __syncthreads();
    }
    float rn[2][4], cn[2][4];
#pragma unroll
    for (int p = 0; p < 2; p++)
#pragma unroll
        for (int r = 0; r < 4; r++) rn[p][r] = rnE[i0 + p * 64 + ty * 4 + r];
#pragma unroll
    for (int q = 0; q < 2; q++)
#pragma unroll
        for (int cc = 0; cc < 4; cc++) cn[q][cc] = cnA[j0 + q * 64 + tx * 4 + cc];
#pragma unroll
    for (int p = 0; p < 2; p++)
#pragma unroll
        for (int r = 0; r < 4; r++) {
            int gi = i0 + p * 64 + ty * 4 + r;
#pragma unroll
            for (int q = 0; q < 2; q++) {
                float4 o;
                float d0 = rn[p][r] + cn[q][0] - 2.0f * acc[p][q][r][0];
                float d1 = rn[p][r] + cn[q][1] - 2.0f * acc[p][q][r][1];
                float d2_ = rn[p][r] + cn[q][2] - 2.0f * acc[p][q][r][2];
                float d3 = rn[p][r] + cn[q][3] - 2.0f * acc[p][q][r][3];
                o.x = sqrtf(fmaxf(d0, 1e-12f));
                o.y = sqrtf(fmaxf(d1, 1e-12f));
                o.z = sqrtf(fmaxf(d2_, 1e-12f));
                o.w = sqrtf(fmaxf(d3, 1e-12f));
                *(float4*)&D[(size_t)gi * NG + j0 + q * 64 + tx * 4] = o;
            }
        }
}

// fallback per-row top-16 selection
__global__ void k_select(float* ws, int cs, unsigned long long dOff) {
    int gbl = blockIdx.y; int gb = cs + gbl;
    int w = threadIdx.x >> 6, lane = threadIdx.x & 63;
    int row = blockIdx.x * 4 + w;
    const float* Dbase = ws + dOff + (size_t)gbl * 3 * (size_t)(NG * NG);
    const float* dg = Dbase + (size_t)row * NG;
    const float* dn = Dbase + (size_t)(NG * NG) + (size_t)row * NG;
    const float* dv = Dbase + (size_t)2 * (NG * NG) + (size_t)row * NG;
    float dgv[16], dnv[16], dvv[16];
#pragma unroll
    for (int q = 0; q < 16; q++) {
        dgv[q] = dg[q * 64 + lane];
        dnv[q] = dn[q * 64 + lane];
        dvv[q] = dv[q * 64 + lane];
    }
    float sg = 0, sv = 0, sn = 0;
    for (int it = 0; it < KNN; it++) {
        float best = 3.4e38f; int bc = 1 << 30;
#pragma unroll
        for (int q = 0; q < 16; q++) { float v = dgv[q]; int c = q * 64 + lane; if (v < best) { best = v; bc = c; } }
#pragma unroll
        for (int off = 32; off; off >>= 1) {
            float ov = __shfl_xor(best, off); int oc = __shfl_xor(bc, off);
            if (ov < best || (ov == best && oc < bc)) { best = ov; bc = oc; }
        }
        sg += best;
        int bq = bc >> 6, bl = bc & 63;
        float t = 0;
#pragma unroll
        for (int q = 0; q < 16; q++) if (q == bq) t = dvv[q];
        t = __shfl(t, bl); sv += t;
        if (lane == bl) {
#pragma unroll
            for (int q = 0; q < 16; q++) if (q == bq) dgv[q] = 3.4e38f;
        }
    }
    for (int it = 0; it < KNN; it++) {
        float best = 3.4e38f; int bc = 1 << 30;
#pragma unroll
        for (int q = 0; q < 16; q++) { float v = dnv[q]; int c = q * 64 + lane; if (v < best) { best = v; bc = c; } }
#pragma unroll
        for (int off = 32; off; off >>= 1) {
            float ov = __shfl_xor(best, off); int oc = __shfl_xor(bc, off);
            if (ov < best || (ov == best && oc < bc)) { best = ov; bc = oc; }
        }
        sn += best;
        int bq = bc >> 6, bl = bc & 63;
        if (lane == bl) {
#pragma unroll
            for (int q = 0; q < 16; q++) if (q == bq) dnv[q] = 3.4e38f;
        }
    }
    __shared__ float ssum[4][3];
    if (lane == 0) { ssum[w][0] = sg; ssum[w][1] = sn; ssum[w][2] = sv; }
    __syncthreads();
    if (threadIdx.x == 0) {
        float* part = ws + OFF_PART + ((size_t)gb * 256 + blockIdx.x) * 3;
        part[0] = ssum[0][0] + ssum[1][0] + ssum[2][0] + ssum[3][0];
        part[1] = ssum[0][1] + ssum[1][1] + ssum[2][1] + ssum[3][1];
        part[2] = ssum[0][2] + ssum[1][2] + ssum[2][2] + ssum[3][2];
    }
}

__global__ void k_reduce(float* ws, float* out, int n) {
    double s[3] = {0, 0, 0};
    for (int idx = threadIdx.x; idx < n; idx += 256) {
        const float* p = ws + OFF_PART + (size_t)idx * 3;
        s[0] += p[0]; s[1] += p[1]; s[2] += p[2];
    }
    __shared__ double red[256];
    for (int m = 0; m < 3; m++) {
        red[threadIdx.x] = s[m]; __syncthreads();
        for (int off = 128; off; off >>= 1) { if (threadIdx.x < off) red[threadIdx.x] += red[threadIdx.x + off]; __syncthreads(); }
        if (threadIdx.x == 0) out[m] = (float)(red[0] / 524288.0 / 8.0);
        __syncthreads();
    }
}

extern "C" void kernel_launch(void* const* d_in, const int* in_sizes, int n_in,
                              void* d_out, int out_size, void* d_ws, size_t ws_size,
                              hipStream_t stream) {
    const float* ex = (const float*)d_in[0];
    const float* ac = (const float*)d_in[1];
    float* ws = (float*)d_ws;
    float* out = (float*)d_out;

    hipLaunchKernelGGL(k_bg, dim3(32), dim3(256), 0, stream, ex, ac, ws);
    hipLaunchKernelGGL(k_order, dim3(1), dim3(1024), 0, stream, ws);
    hipLaunchKernelGGL(k_gather, dim3(FF, NGB), dim3(256), 0, stream, ex, ac, ws);
    hipLaunchKernelGGL(k_meanfin, dim3(NGB, 2), dim3(64), 0, stream, ws);
    hipLaunchKernelGGL(k_std, dim3(NGB, FF, 2), dim3(128), 0, stream, ws);
    hipLaunchKernelGGL(k_derive, dim3(KF, NGB), dim3(256), 0, stream, ws);

    size_t ws_floats = ws_size / 4;
    bool fast = ws_floats >= (size_t)FAST_END;

    if (fast) {
        hipLaunchKernelGGL(k_tobf16, dim3(48, NGB, 6), dim3(256), 0, stream, ws);
        hipLaunchKernelGGL(k_normfin, dim3(6, NGB), dim3(256), 0, stream, ws);
        hipLaunchKernelGGL((k_fsel<2>), dim3(16, NGB), dim3(256), 0, stream, ws);
        hipLaunchKernelGGL((k_fsel<1>), dim3(16, NGB), dim3(256), 0, stream, ws);
        hipLaunchKernelGGL(k_reduce, dim3(1), dim3(256), 0, stream, ws, out, 512);
    } else {
        hipLaunchKernelGGL(k_norms, dim3(6, NGB), dim3(256), 0, stream, ws);
        size_t dcap = (ws_floats > (size_t)OFF_D) ? (ws_floats - (size_t)OFF_D) : 0;
        int gbc = (int)(dcap / (3ull * NG * NG));
        if (gbc < 1) gbc = 1;
        if (gbc > 32) gbc = 32;
        for (int cs = 0; cs < NGB; cs += gbc) {
            int take = (NGB - cs < gbc) ? (NGB - cs) : gbc;
            hipLaunchKernelGGL(k_gemm, dim3(8, 8, take * 3), dim3(16, 16), 0, stream, ws, cs);
            hipLaunchKernelGGL(k_select, dim3(256, take), dim3(256), 0, stream, ws, cs, (unsigned long long)OFF_D);
        }
        hipLaunchKernelGGL(k_reduce, dim3(1), dim3(256), 0, stream, ws, out, 8192);
    }
}

// Round 5
// 645.713 us; speedup vs baseline: 3.1004x; 3.1004x over previous
//
#include <hip/hip_runtime.h>
#include <math.h>

#define GGRP 8
#define NPTS 8192
#define NG   1024      // points per group
#define BB   4
#define FF   64
#define CH   11
#define KF   192       // feature dim F*3
#define NGB  32        // G*B
#define KNN  16

// ws offsets in FLOATS
#define OFF_ORD_E  0        // 8192 int
#define OFF_ORD_A  8192     // 8192 int
#define OFF_MEAN_E 32768    // 96 f
#define OFF_MEAN_A 32896    // 96 f
#define OFF_MEANP  37888    // 2*32*64*3 = 12288 f
#define OFF_PART   50176    // up to 8192*3 f
#define OFF_NORMP  74752    // 6*32*3*1024 = 589824 f
#define OFF_NORMS  664576   // 6*32*1024 = 196608 f
#define OFF_MAT    1048576
#define MATSZ      6291456  // 32*192*1024 floats per matrix-set
#define OFF_BMAT   38797312 // OFF_MAT + 6*MATSZ ; bf16 mats (fast) / D (fallback)
#define BMAT_FLOATS 18874368
#define FAST_END   57671680 // OFF_BMAT + BMAT_FLOATS
#define OFF_D      38797312 // fallback D region
// matrix order: 0 PE, 1 PA, 2 VE, 3 VA, 4 NPE, 5 NPA

typedef short bf16x8 __attribute__((ext_vector_type(8)));
typedef float f32x4 __attribute__((ext_vector_type(4)));

// fused argmax-group + stable counting-compaction; one block per side
__global__ void k_order(const float* __restrict__ ex, const float* __restrict__ ac, float* ws) {
    int side = blockIdx.x;
    const float* src = side ? ac : ex;
    int* ord = (int*)ws + (side ? OFF_ORD_A : OFF_ORD_E);
    __shared__ unsigned char bg[NPTS];
    __shared__ int cnts[8];
    int t = threadIdx.x;
    for (int n = t; n < NPTS; n += 1024) {
        const float* p = src + (size_t)n * CH + 3;
        float m = p[0]; int a = 0;
#pragma unroll
        for (int c = 1; c < GGRP; c++) { float v = p[c]; if (v > m) { m = v; a = c; } }
        bg[n] = (unsigned char)a;
    }
    __syncthreads();
    int w = t >> 6, lane = t & 63;
    if (w < 8) {
        int grp = w;
        int cnt = 0;
        for (int base = 0; base < NPTS; base += 64) {
            unsigned long long m = __ballot(bg[base + lane] == grp);
            cnt += __popcll(m);
        }
        if (lane == 0) cnts[w] = cnt;
    }
    __syncthreads();
    if (w < 8) {
        int grp = w;
        int pos = 0;
        for (int g2 = 0; g2 < grp; g2++) pos += cnts[g2];
        for (int base = 0; base < NPTS; base += 64) {
            int hit = (bg[base + lane] == grp);
            unsigned long long m = __ballot(hit);
            int pre = __popcll(m & ((1ull << lane) - 1ull));
            if (hit) { int slot = pos + pre; if (slot < NPTS) ord[slot] = base + lane; }
            pos += __popcll(m);
        }
    }
}

// build PE_T / PA_T : layout [gb][k=f*3+c][i] ; per-(gb,f) coord-sum partials.
// fully unrolled: all gathers issued before stores for MLP.
__global__ void k_gather(const float* __restrict__ ex, const float* __restrict__ ac, float* ws) {
    int f = blockIdx.x, gb = blockIdx.y;
    int g = gb >> 2, b = gb & 3;
    const int* __restrict__ ord_e = (const int*)ws + OFF_ORD_E + g * NG;
    const int* __restrict__ ord_a = (const int*)ws + OFF_ORD_A + g * NG;
    float* __restrict__ PE = ws + OFF_MAT + ((size_t)gb * KF + f * 3) * NG;
    float* __restrict__ PA = PE + (size_t)MATSZ;
    size_t sbase = ((size_t)(b * FF + f)) * NPTS;
    const float* __restrict__ exb = ex + sbase * CH;
    const float* __restrict__ acb = ac + sbase * CH;
    int t = threadIdx.x;
    int ne[4], na[4];
#pragma unroll
    for (int it = 0; it < 4; it++) { ne[it] = ord_e[t + it * 256]; na[it] = ord_a[t + it * 256]; }
    float e[4][3], a[4][3];
#pragma unroll
    for (int it = 0; it < 4; it++) {
        const float* p = exb + (size_t)ne[it] * CH;
        e[it][0] = p[0]; e[it][1] = p[1]; e[it][2] = p[2];
        const float* q = acb + (size_t)na[it] * CH;
        a[it][0] = q[0]; a[it][1] = q[1]; a[it][2] = q[2];
    }
    float sums[6] = {0, 0, 0, 0, 0, 0};
#pragma unroll
    for (int it = 0; it < 4; it++) {
        int i = t + it * 256;
        PE[i] = e[it][0]; PE[NG + i] = e[it][1]; PE[2 * NG + i] = e[it][2];
        PA[i] = a[it][0]; PA[NG + i] = a[it][1]; PA[2 * NG + i] = a[it][2];
        sums[0] += e[it][0]; sums[1] += e[it][1]; sums[2] += e[it][2];
        sums[3] += a[it][0]; sums[4] += a[it][1]; sums[5] += a[it][2];
    }
    __shared__ float red[256];
    for (int c = 0; c < 6; c++) {
        red[t] = sums[c]; __syncthreads();
        for (int off = 128; off; off >>= 1) { if (t < off) red[t] += red[t + off]; __syncthreads(); }
        if (t == 0) {
            int side = c / 3;
            ws[OFF_MEANP + ((size_t)(side * NGB + gb) * FF + f) * 3 + (c % 3)] = red[0];
        }
        __syncthreads();
    }
}

// fused mean-finalize + std (ddof=1, own-mean two-sum) + derive (V, NP)
// grid (FF, NGB, 2), block 128; rows for (gb,f,side) kept in registers.
__global__ void k_stats(float* ws) {
    int f = blockIdx.x, gb = blockIdx.y, side = blockIdx.z;
    int t = threadIdx.x;
    const float* __restrict__ mp = ws + OFF_MEANP + ((size_t)(side * NGB + gb) * FF) * 3;
    __shared__ float smean[3];
    if (t < 64) {
        float v0 = mp[t * 3], v1 = mp[t * 3 + 1], v2 = mp[t * 3 + 2];
#pragma unroll
        for (int off = 32; off; off >>= 1) {
            v0 += __shfl_xor(v0, off); v1 += __shfl_xor(v1, off); v2 += __shfl_xor(v2, off);
        }
        if (t == 0) { smean[0] = v0 / 65536.0f; smean[1] = v1 / 65536.0f; smean[2] = v2 / 65536.0f; }
    }
    __syncthreads();
    float m0 = smean[0], m1 = smean[1], m2 = smean[2];
    const float* __restrict__ P = ws + OFF_MAT + (size_t)side * MATSZ + ((size_t)gb * KF + f * 3) * NG;
    float vals[24];
    float s1 = 0, s2 = 0;
#pragma unroll
    for (int j = 0; j < 24; j++) {
        int idx = t + j * 128;
        float raw = P[idx];
        float mm = (j < 8) ? m0 : ((j < 16) ? m1 : m2);
        float v = raw - mm;
        vals[j] = raw;
        s1 += v; s2 += v * v;
    }
    __shared__ float redA[128], redB[128];
    redA[t] = s1; redB[t] = s2; __syncthreads();
    for (int off = 64; off; off >>= 1) {
        if (t < off) { redA[t] += redA[t + off]; redB[t] += redB[t + off]; }
        __syncthreads();
    }
    __shared__ float srs;
    if (t == 0) {
        float var = (redB[0] - redA[0] * redA[0] / 3072.0f) / 3071.0f;
        srs = 1.0f / sqrtf(fmaxf(var, 0.0f));
    }
    __syncthreads();
    float rs = srs;
    float* __restrict__ V = ws + OFF_MAT + (size_t)(2 + side) * MATSZ + ((size_t)gb * KF + f * 3) * NG;
    float* __restrict__ NP = ws + OFF_MAT + (size_t)(4 + side) * MATSZ + ((size_t)gb * KF + f * 3) * NG;
    const float* __restrict__ Pp = P - 3 * NG;
#pragma unroll
    for (int j = 0; j < 24; j++) {
        int idx = t + j * 128;
        float mm = (j < 8) ? m0 : ((j < 16) ? m1 : m2);
        NP[idx] = (vals[j] - mm) * rs;
        V[idx] = f ? (vals[j] - Pp[idx]) : 0.0f;
    }
}

// fallback-path norms (fp32 mats)
__global__ void k_norms(float* ws) {
    int mat = blockIdx.x, gb = blockIdx.y;
    const float* M = ws + OFF_MAT + (size_t)mat * MATSZ + (size_t)gb * KF * NG;
    float* nr = ws + OFF_NORMS + ((size_t)mat * NGB + gb) * NG;
    for (int i = threadIdx.x; i < NG; i += 256) {
        float s = 0;
        for (int k = 0; k < KF; k++) { float v = M[(size_t)k * NG + i]; s += v * v; }
        nr[i] = s;
    }
}

// transpose-convert fp32 [k][i] -> bf16 row-major [i][k] ; fold ||.||^2 partials
__global__ void k_tobf16(float* ws) {
    int x = blockIdx.x;            // 0..47: it = x&15, kt = x>>4
    int it = x & 15, kt = x >> 4;
    int gb = blockIdx.y, mat = blockIdx.z;
    const float* M = ws + OFF_MAT + (size_t)mat * MATSZ + (size_t)gb * KF * NG;
    unsigned short* out = (unsigned short*)(ws + OFF_BMAT) + ((size_t)mat * NGB + gb) * (size_t)(NG * KF);
    float* normp = ws + OFF_NORMP + ((size_t)(mat * NGB + gb) * 3 + kt) * NG;
    __shared__ float tile[64][65];
    int i0 = it * 64, k0 = kt * 64;
    int t = threadIdx.x;
    int ii = t & 63, kq = t >> 6;
#pragma unroll
    for (int rep = 0; rep < 16; rep++) {
        int kk = kq + rep * 4;
        tile[kk][ii] = M[(size_t)(k0 + kk) * NG + i0 + ii];
    }
    __syncthreads();
    int kk2 = t & 63, iq = t >> 6;
#pragma unroll
    for (int rep = 0; rep < 16; rep++) {
        int i2 = iq + rep * 4;
        float v = tile[kk2][i2];
        unsigned u = __builtin_bit_cast(unsigned, v);
        unsigned r = (u + 0x7fffu + ((u >> 16) & 1u)) >> 16;   // RNE bf16
        out[(size_t)(i0 + i2) * KF + k0 + kk2] = (unsigned short)r;
        float nsq = v * v;
#pragma unroll
        for (int off = 32; off; off >>= 1) nsq += __shfl_xor(nsq, off);
        if (kk2 == 0) normp[i0 + i2] = nsq;
    }
}

__global__ void k_normfin(float* ws) {
    int mat = blockIdx.x, gb = blockIdx.y;
    const float* np = ws + OFF_NORMP + (size_t)(mat * NGB + gb) * 3 * NG;
    float* nr = ws + OFF_NORMS + ((size_t)mat * NGB + gb) * NG;
    for (int i = threadIdx.x; i < NG; i += 256)
        nr[i] = np[i] + np[NG + i] + np[2 * NG + i];
}

// MFMA distance GEMM: 128x128 tile, 4 waves (2x2), BK=64, swizzled LDS.
// Stores CLAMPED SQUARED distances (selection is monotone-invariant).
__global__ __launch_bounds__(256) void k_mgemm(float* ws, int cs, unsigned long long dOff) {
    int bx = blockIdx.x, by = blockIdx.y;
    int bz = blockIdx.z; int gbl = bz / 3, m3 = bz % 3;
    int gb = cs + gbl;
    int eIdx = (m3 == 0) ? 0 : ((m3 == 1) ? 4 : 2);
    int aIdx = (m3 == 0) ? 1 : ((m3 == 1) ? 5 : 3);
    const unsigned short* bmat = (const unsigned short*)(ws + OFF_BMAT);
    const unsigned short* Eg = bmat + ((size_t)eIdx * NGB + gb) * (size_t)(NG * KF);
    const unsigned short* Ag = bmat + ((size_t)aIdx * NGB + gb) * (size_t)(NG * KF);
    const float* rnE = ws + OFF_NORMS + ((size_t)eIdx * NGB + gb) * NG;
    const float* cnA = ws + OFF_NORMS + ((size_t)aIdx * NGB + gb) * NG;
    float* D = ws + dOff + ((size_t)gbl * 3 + m3) * (size_t)(NG * NG);
    int i0 = by * 128, j0 = bx * 128;
    __shared__ unsigned short lE[128 * 64];
    __shared__ unsigned short lA[128 * 64];
    int tid = threadIdx.x;
    int wid = tid >> 6, lane = tid & 63;
    int wr = wid >> 1, wc = wid & 1;
    f32x4 acc[4][4];
#pragma unroll
    for (int m = 0; m < 4; m++)
#pragma unroll
        for (int n = 0; n < 4; n++) acc[m][n] = (f32x4){0.f, 0.f, 0.f, 0.f};

    int rr = lane >> 3, ss = lane & 7;
    for (int k0 = 0; k0 < KF; k0 += 64) {
        if (k0) __syncthreads();
#pragma unroll
        for (int q = 0; q < 4; q++) {
            int r0 = wid * 32 + q * 8;
            int r = r0 + rr;
            int c = ss ^ (r & 7);
            __builtin_amdgcn_global_load_lds(
                (const __attribute__((address_space(1))) void*)(Eg + (size_t)(i0 + r) * KF + k0 + c * 8),
                (__attribute__((address_space(3))) void*)&lE[r0 * 64], 16, 0, 0);
            __builtin_amdgcn_global_load_lds(
                (const __attribute__((address_space(1))) void*)(Ag + (size_t)(j0 + r) * KF + k0 + c * 8),
                (__attribute__((address_space(3))) void*)&lA[r0 * 64], 16, 0, 0);
        }
        asm volatile("s_waitcnt vmcnt(0)" ::: "memory");
        __syncthreads();
#pragma unroll
        for (int ks = 0; ks < 2; ks++) {
            bf16x8 af[4], bfr[4];
            int kb = ks * 64 + (lane >> 4) * 16;
#pragma unroll
            for (int m = 0; m < 4; m++) {
                int arow = wr * 64 + m * 16 + (lane & 15);
                af[m] = *(const bf16x8*)((const char*)lE + arow * 128 + (kb ^ ((arow & 7) << 4)));
            }
#pragma unroll
            for (int n = 0; n < 4; n++) {
                int brow = wc * 64 + n * 16 + (lane & 15);
                bfr[n] = *(const bf16x8*)((const char*)lA + brow * 128 + (kb ^ ((brow & 7) << 4)));
            }
#pragma unroll
            for (int m = 0; m < 4; m++)
#pragma unroll
                for (int n = 0; n < 4; n++)
                    acc[m][n] = __builtin_amdgcn_mfma_f32_16x16x32_bf16(af[m], bfr[n], acc[m][n], 0, 0, 0);
        }
    }

    int colbase = j0 + wc * 64 + (lane & 15);
    int rowbase = i0 + wr * 64 + ((lane >> 4) << 2);
    float cn[4];
#pragma unroll
    for (int n = 0; n < 4; n++) cn[n] = cnA[colbase + n * 16];
#pragma unroll
    for (int m = 0; m < 4; m++) {
        int rb = rowbase + m * 16;
#pragma unroll
        for (int r = 0; r < 4; r++) {
            float rn = rnE[rb + r];
#pragma unroll
            for (int n = 0; n < 4; n++) {
                float d = rn + cn[n] - 2.0f * acc[m][n][r];
                D[(size_t)(rb + r) * NG + colbase + n * 16] = fmaxf(d, 1e-12f);
            }
        }
    }
}

// fallback fp32 GEMM (small-ws path) — also stores clamped squared distances
__global__ __launch_bounds__(256) void k_gemm(float* ws, int cs) {
    int bx = blockIdx.x, by = blockIdx.y;
    int bz = blockIdx.z; int gbl = bz / 3, m = bz % 3;
    int gb = cs + gbl;
    int eIdx = (m == 0) ? 0 : ((m == 1) ? 4 : 2);
    int aIdx = (m == 0) ? 1 : ((m == 1) ? 5 : 3);
    const float* E = ws + OFF_MAT + (size_t)eIdx * MATSZ + (size_t)gb * KF * NG;
    const float* A = ws + OFF_MAT + (size_t)aIdx * MATSZ + (size_t)gb * KF * NG;
    const float* rnE = ws + OFF_NORMS + ((size_t)eIdx * NGB + gb) * NG;
    const float* cnA = ws + OFF_NORMS + ((size_t)aIdx * NGB + gb) * NG;
    float* D = ws + OFF_D + ((size_t)gbl * 3 + m) * (size_t)(NG * NG);
    int i0 = by * 128, j0 = bx * 128;
    __shared__ float4 Et[8][32], At[8][32];
    int tx = threadIdx.x, ty = threadIdx.y;
    int tid = ty * 16 + tx;
    float acc[2][2][4][4] = {};
    for (int k0 = 0; k0 < KF; k0 += 8) {
        {
            int kk = tid >> 5, i4 = tid & 31;
            Et[kk][i4] = *(const float4*)&E[(size_t)(k0 + kk) * NG + i0 + i4 * 4];
            At[kk][i4] = *(const float4*)&A[(size_t)(k0 + kk) * NG + j0 + i4 * 4];
        }
        __syncthreads();
#pragma unroll
        for (int kk = 0; kk < 8; kk++) {
            float4 e0 = Et[kk][ty], e1 = Et[kk][16 + ty];
            float4 a0 = At[kk][tx], a1 = At[kk][16 + tx];
            float er[2][4] = {{e0.x, e0.y, e0.z, e0.w}, {e1.x, e1.y, e1.z, e1.w}};
            float ar[2][4] = {{a0.x, a0.y, a0.z, a0.w}, {a1.x, a1.y, a1.z, a1.w}};
#pragma unroll
            for (int p = 0; p < 2; p++)
#pragma unroll
                for (int q = 0; q < 2; q++)
#pragma unroll
                    for (int r = 0; r < 4; r++)
#pragma unroll
                        for (int cc = 0; cc < 4; cc++)
                            acc[p][q][r][cc] += er[p][r] * ar[q][cc];
        }
        __syncthreads();
    }
    float rn[2][4], cn[2][4];
#pragma unroll
    for (int p = 0; p < 2; p++)
#pragma unroll
        for (int r = 0; r < 4; r++) rn[p][r] = rnE[i0 + p * 64 + ty * 4 + r];
#pragma unroll
    for (int q = 0; q < 2; q++)
#pragma unroll
        for (int cc = 0; cc < 4; cc++) cn[q][cc] = cnA[j0 + q * 64 + tx * 4 + cc];
#pragma unroll
    for (int p = 0; p < 2; p++)
#pragma unroll
        for (int r = 0; r < 4; r++) {
            int gi = i0 + p * 64 + ty * 4 + r;
#pragma unroll
            for (int q = 0; q < 2; q++) {
                float4 o;
                o.x = fmaxf(rn[p][r] + cn[q][0] - 2.0f * acc[p][q][r][0], 1e-12f);
                o.y = fmaxf(rn[p][r] + cn[q][1] - 2.0f * acc[p][q][r][1], 1e-12f);
                o.z = fmaxf(rn[p][r] + cn[q][2] - 2.0f * acc[p][q][r][2], 1e-12f);
                o.w = fmaxf(rn[p][r] + cn[q][3] - 2.0f * acc[p][q][r][3], 1e-12f);
                *(float4*)&D[(size_t)gi * NG + j0 + q * 64 + tx * 4] = o;
            }
        }
}

// per-row top-16 selection on squared distances; sqrt only on selected values
__global__ void k_select(float* ws, int cs, unsigned long long dOff) {
    int gbl = blockIdx.y; int gb = cs + gbl;
    int w = threadIdx.x >> 6, lane = threadIdx.x & 63;
    int row = blockIdx.x * 4 + w;
    const float* Dbase = ws + dOff + (size_t)gbl * 3 * (size_t)(NG * NG);
    const float* dg = Dbase + (size_t)row * NG;
    const float* dn = Dbase + (size_t)(NG * NG) + (size_t)row * NG;
    const float* dv = Dbase + (size_t)2 * (NG * NG) + (size_t)row * NG;
    float dgv[16], dnv[16], dvv[16];
#pragma unroll
    for (int q = 0; q < 16; q++) {
        dgv[q] = dg[q * 64 + lane];
        dnv[q] = dn[q * 64 + lane];
        dvv[q] = dv[q * 64 + lane];
    }
    float sg = 0, sv = 0, sn = 0;
    for (int it = 0; it < KNN; it++) {
        float best = 3.4e38f; int bc = 1 << 30;
#pragma unroll
        for (int q = 0; q < 16; q++) { float v = dgv[q]; int c = q * 64 + lane; if (v < best) { best = v; bc = c; } }
#pragma unroll
        for (int off = 32; off; off >>= 1) {
            float ov = __shfl_xor(best, off); int oc = __shfl_xor(bc, off);
            if (ov < best || (ov == best && oc < bc)) { best = ov; bc = oc; }
        }
        sg += sqrtf(best);
        int bq = bc >> 6, bl = bc & 63;
        float t = 0;
#pragma unroll
        for (int q = 0; q < 16; q++) if (q == bq) t = dvv[q];
        t = __shfl(t, bl); sv += sqrtf(t);
        if (lane == bl) {
#pragma unroll
            for (int q = 0; q < 16; q++) if (q == bq) dgv[q] = 3.4e38f;
        }
    }
    for (int it = 0; it < KNN; it++) {
        float best = 3.4e38f; int bc = 1 << 30;
#pragma unroll
        for (int q = 0; q < 16; q++) { float v = dnv[q]; int c = q * 64 + lane; if (v < best) { best = v; bc = c; } }
#pragma unroll
        for (int off = 32; off; off >>= 1) {
            float ov = __shfl_xor(best, off); int oc = __shfl_xor(bc, off);
            if (ov < best || (ov == best && oc < bc)) { best = ov; bc = oc; }
        }
        sn += sqrtf(best);
        int bq = bc >> 6, bl = bc & 63;
        if (lane == bl) {
#pragma unroll
            for (int q = 0; q < 16; q++) if (q == bq) dnv[q] = 3.4e38f;
        }
    }
    __shared__ float ssum[4][3];
    if (lane == 0) { ssum[w][0] = sg; ssum[w][1] = sn; ssum[w][2] = sv; }
    __syncthreads();
    if (threadIdx.x == 0) {
        float* part = ws + OFF_PART + ((size_t)gb * 256 + blockIdx.x) * 3;
        part[0] = ssum[0][0] + ssum[1][0] + ssum[2][0] + ssum[3][0];
        part[1] = ssum[0][1] + ssum[1][1] + ssum[2][1] + ssum[3][1];
        part[2] = ssum[0][2] + ssum[1][2] + ssum[2][2] + ssum[3][2];
    }
}

__global__ void k_reduce(float* ws, float* out, int n) {
    double s[3] = {0, 0, 0};
    for (int idx = threadIdx.x; idx < n; idx += 256) {
        const float* p = ws + OFF_PART + (size_t)idx * 3;
        s[0] += p[0]; s[1] += p[1]; s[2] += p[2];
    }
    __shared__ double red[256];
    for (int m = 0; m < 3; m++) {
        red[threadIdx.x] = s[m]; __syncthreads();
        for (int off = 128; off; off >>= 1) { if (threadIdx.x < off) red[threadIdx.x] += red[threadIdx.x + off]; __syncthreads(); }
        if (threadIdx.x == 0) out[m] = (float)(red[0] / 524288.0 / 8.0);
        __syncthreads();
    }
}

extern "C" void kernel_launch(void* const* d_in, const int* in_sizes, int n_in,
                              void* d_out, int out_size, void* d_ws, size_t ws_size,
                              hipStream_t stream) {
    const float* ex = (const float*)d_in[0];
    const float* ac = (const float*)d_in[1];
    float* ws = (float*)d_ws;
    float* out = (float*)d_out;

    hipLaunchKernelGGL(k_order, dim3(2), dim3(1024), 0, stream, ex, ac, ws);
    hipLaunchKernelGGL(k_gather, dim3(FF, NGB), dim3(256), 0, stream, ex, ac, ws);
    hipLaunchKernelGGL(k_stats, dim3(FF, NGB, 2), dim3(128), 0, stream, ws);

    size_t ws_floats = ws_size / 4;
    bool fast = ws_floats >= (size_t)FAST_END;

    if (fast) {
        hipLaunchKernelGGL(k_tobf16, dim3(48, NGB, 6), dim3(256), 0, stream, ws);
        hipLaunchKernelGGL(k_normfin, dim3(6, NGB), dim3(256), 0, stream, ws);
        int gbc = 8;  // D overlays the dead fp32-mat region (6*MATSZ = exactly 8*3*NG*NG)
        for (int cs = 0; cs < NGB; cs += gbc) {
            int take = (NGB - cs < gbc) ? (NGB - cs) : gbc;
            hipLaunchKernelGGL(k_mgemm, dim3(8, 8, take * 3), dim3(256), 0, stream, ws, cs, (unsigned long long)OFF_MAT);
            hipLaunchKernelGGL(k_select, dim3(256, take), dim3(256), 0, stream, ws, cs, (unsigned long long)OFF_MAT);
        }
        hipLaunchKernelGGL(k_reduce, dim3(1), dim3(256), 0, stream, ws, out, 8192);
    } else {
        hipLaunchKernelGGL(k_norms, dim3(6, NGB), dim3(256), 0, stream, ws);
        size_t dcap = (ws_floats > (size_t)OFF_D) ? (ws_floats - (size_t)OFF_D) : 0;
        int gbc = (int)(dcap / (3ull * NG * NG));
        if (gbc < 1) gbc = 1;
        if (gbc > 32) gbc = 32;
        for (int cs = 0; cs < NGB; cs += gbc) {
            int take = (NGB - cs < gbc) ? (NGB - cs) : gbc;
            hipLaunchKernelGGL(k_gemm, dim3(8, 8, take * 3), dim3(16, 16), 0, stream, ws, cs);
            hipLaunchKernelGGL(k_select, dim3(256, take), dim3(256), 0, stream, ws, cs, (unsigned long long)OFF_D);
        }
        hipLaunchKernelGGL(k_reduce, dim3(1), dim3(256), 0, stream, ws, out, 8192);
    }
}

// Round 6
// 580.621 us; speedup vs baseline: 3.4480x; 1.1121x over previous
//
#include <hip/hip_runtime.h>
#include <math.h>

#define GGRP 8
#define NPTS 8192
#define NG   1024      // points per group
#define BB   4
#define FF   64
#define CH   11
#define KF   192       // feature dim F*3
#define NGB  32        // G*B
#define KNN  16

// ws offsets in FLOATS
#define OFF_ORD_E  0        // 8192 int
#define OFF_ORD_A  8192     // 8192 int
#define OFF_BG_E   16384    // 8192 int
#define OFF_BG_A   24576    // 8192 int
#define OFF_MEAN_E 32768    // 96 f
#define OFF_MEAN_A 32896    // 96 f
#define OFF_STD_E  33024    // 2048 f (stores 1/std)
#define OFF_STD_A  35072    // 2048 f
#define OFF_MEANP  37888    // 2*32*64*3 = 12288 f
#define OFF_PART   50176    // up to 8192*3 f
#define OFF_NORMP  74752    // 6*32*3*1024 = 589824 f
#define OFF_NORMS  664576   // 6*32*1024 = 196608 f
#define OFF_MAT    1048576
#define MATSZ      6291456  // 32*192*1024 floats per matrix-set
#define OFF_BMAT   38797312 // OFF_MAT + 6*MATSZ ; bf16 mats ; D overlays OFF_MAT (12 gb cap)
#define BMAT_FLOATS 18874368
#define FAST_END   57671680 // OFF_BMAT + BMAT_FLOATS
#define OFF_D      38797312 // fallback D region
// logical matrix order: 0 PE, 1 PA, 2 VE, 3 VA, 4 NPE, 5 NPA

typedef short bf16x8 __attribute__((ext_vector_type(8)));
typedef float f32x4 __attribute__((ext_vector_type(4)));

__device__ __forceinline__ unsigned short f2bf(float v) {
    unsigned u = __builtin_bit_cast(unsigned, v);
    return (unsigned short)((u + 0x7fffu + ((u >> 16) & 1u)) >> 16);   // RNE
}

__global__ void k_bg(const float* __restrict__ ex, const float* __restrict__ ac, float* ws) {
    int n = blockIdx.x * blockDim.x + threadIdx.x;
    if (n >= NPTS) return;
    int* bg_e = (int*)ws + OFF_BG_E;
    int* bg_a = (int*)ws + OFF_BG_A;
    const float* pe = ex + (size_t)n * CH + 3;
    const float* pa = ac + (size_t)n * CH + 3;
    float m = -1e30f; int a = 0;
#pragma unroll
    for (int c = 0; c < GGRP; c++) { float v = pe[c]; if (v > m) { m = v; a = c; } }
    bg_e[n] = a;
    m = -1e30f; a = 0;
#pragma unroll
    for (int c = 0; c < GGRP; c++) { float v = pa[c]; if (v > m) { m = v; a = c; } }
    bg_a[n] = a;
}

// stable counting-compaction: 16 waves, wave w<8 -> expected group w, w>=8 -> actual group w-8
__global__ void k_order(float* ws) {
    int tid = threadIdx.x;
    int w = tid >> 6, lane = tid & 63;
    const int* bg = (const int*)ws + ((w < 8) ? OFF_BG_E : OFF_BG_A);
    int* ord = (int*)ws + ((w < 8) ? OFF_ORD_E : OFF_ORD_A);
    int grp = w & 7;
    __shared__ int cnts[16];
    int cnt = 0;
    for (int base = 0; base < NPTS; base += 64) {
        unsigned long long m = __ballot(bg[base + lane] == grp);
        cnt += __popcll(m);
    }
    if (lane == 0) cnts[w] = cnt;
    __syncthreads();
    int pos = 0;
    for (int g2 = 0; g2 < grp; g2++) pos += cnts[(w & 8) | g2];
    for (int base = 0; base < NPTS; base += 64) {
        int hit = (bg[base + lane] == grp);
        unsigned long long m = __ballot(hit);
        int pre = __popcll(m & ((1ull << lane) - 1ull));
        if (hit) { int slot = pos + pre; if (slot < NPTS) ord[slot] = base + lane; }
        pos += __popcll(m);
    }
}

// one block per (f, b, side): full-permutation gather over the whole slab
// (slab is L2-resident -> every line fetched once). Writes P fp32 [k][i],
// plus per-(g,c) mean partials.
__global__ __launch_bounds__(512) void k_gather(const float* __restrict__ ex, const float* __restrict__ ac, float* ws) {
    int f = blockIdx.x, b = blockIdx.y, side = blockIdx.z;
    const int* __restrict__ ord = (const int*)ws + (side ? OFF_ORD_A : OFF_ORD_E);
    const float* __restrict__ src = (side ? ac : ex) + ((size_t)(b * FF + f) * NPTS) * CH;
    float* __restrict__ P = ws + OFF_MAT + (size_t)side * MATSZ;
    int t = threadIdx.x;
    int w = t >> 6, lane = t & 63;

    int idxs[16];
#pragma unroll
    for (int it = 0; it < 16; it++) idxs[it] = ord[it * 512 + t];
    float px[16], py[16], pz[16];
#pragma unroll
    for (int it = 0; it < 16; it++) {
        const float* p = src + (size_t)idxs[it] * CH;
        px[it] = p[0]; py[it] = p[1]; pz[it] = p[2];
    }
    __shared__ float accum[8][24];
#pragma unroll
    for (int g = 0; g < 8; g++) {
        float s0 = 0, s1 = 0, s2 = 0;
#pragma unroll
        for (int h = 0; h < 2; h++) {
            int it = g * 2 + h;
            int col = h * 512 + t;
            size_t mb = ((size_t)((g * 4 + b) * KF + f * 3)) * NG + col;
            P[mb] = px[it]; P[mb + NG] = py[it]; P[mb + 2 * NG] = pz[it];
            s0 += px[it]; s1 += py[it]; s2 += pz[it];
        }
#pragma unroll
        for (int off = 32; off; off >>= 1) {
            s0 += __shfl_xor(s0, off); s1 += __shfl_xor(s1, off); s2 += __shfl_xor(s2, off);
        }
        if (lane == 0) { accum[w][g * 3] = s0; accum[w][g * 3 + 1] = s1; accum[w][g * 3 + 2] = s2; }
    }
    __syncthreads();
    if (t < 24) {
        float s = 0;
#pragma unroll
        for (int wv = 0; wv < 8; wv++) s += accum[wv][t];
        int g = t / 3, c = t % 3;
        ws[OFF_MEANP + ((size_t)(side * NGB + (g * 4 + b)) * FF + f) * 3 + c] = s;
    }
}

__global__ void k_meanfin(float* ws) {
    int gb = blockIdx.x, side = blockIdx.y;
    int lane = threadIdx.x;
    const float* mp = ws + OFF_MEANP + ((size_t)(side * NGB + gb) * FF) * 3;
    float s0 = mp[lane * 3], s1 = mp[lane * 3 + 1], s2 = mp[lane * 3 + 2];
#pragma unroll
    for (int off = 32; off; off >>= 1) {
        s0 += __shfl_xor(s0, off); s1 += __shfl_xor(s1, off); s2 += __shfl_xor(s2, off);
    }
    if (lane == 0) {
        float* m = ws + (side ? OFF_MEAN_A : OFF_MEAN_E) + gb * 3;
        m[0] = s0 / 65536.0f; m[1] = s1 / 65536.0f; m[2] = s2 / 65536.0f;
    }
}

// std over (n,3) of centered data, ddof=1 (two-sum form); stores 1/std
__global__ void k_std(float* ws) {
    int f = blockIdx.x, gb = blockIdx.y, side = blockIdx.z;
    int t = threadIdx.x;
    const float* __restrict__ P = ws + OFF_MAT + (size_t)side * MATSZ + ((size_t)gb * KF + f * 3) * NG;
    const float* mean = ws + (side ? OFF_MEAN_A : OFF_MEAN_E) + gb * 3;
    float m0 = mean[0], m1 = mean[1], m2 = mean[2];
    float s1 = 0, s2 = 0;
#pragma unroll
    for (int j = 0; j < 24; j++) {
        int idx = t + j * 128;
        float mm = (j < 8) ? m0 : ((j < 16) ? m1 : m2);
        float v = P[idx] - mm;
        s1 += v; s2 += v * v;
    }
    __shared__ float redA[128], redB[128];
    redA[t] = s1; redB[t] = s2; __syncthreads();
    for (int off = 64; off; off >>= 1) {
        if (t < off) { redA[t] += redA[t + off]; redB[t] += redB[t + off]; }
        __syncthreads();
    }
    if (t == 0) {
        float var = (redB[0] - redA[0] * redA[0] / 3072.0f) / 3071.0f;
        float* st = ws + (side ? OFF_STD_A : OFF_STD_E);
        st[gb * FF + f] = 1.0f / sqrtf(fmaxf(var, 0.0f));
    }
}

// transpose fp32 P [k][i] -> THREE bf16 mats [i][k] (P, V=P[k]-P[k-3], NP=(P-m)*rs)
// + per-mat ||.||^2 partials. grid (48, NGB, 2), 256 thr.
__global__ void k_tobf3(float* ws) {
    int x = blockIdx.x;
    int it = x & 15, kt = x >> 4;
    int gb = blockIdx.y, side = blockIdx.z;
    const float* __restrict__ P = ws + OFF_MAT + (size_t)side * MATSZ + (size_t)gb * KF * NG;
    unsigned short* bm = (unsigned short*)(ws + OFF_BMAT);
    const float* mean = ws + (side ? OFF_MEAN_A : OFF_MEAN_E) + gb * 3;
    const float* rst = ws + (side ? OFF_STD_A : OFF_STD_E) + gb * FF;
    float m0 = mean[0], m1 = mean[1], m2 = mean[2];
    __shared__ float tile[67][65];   // rows = k0-3 .. k0+63
    int i0 = it * 64, k0 = kt * 64;
    int t = threadIdx.x;
    int ii = t & 63, kq = t >> 6;
#pragma unroll
    for (int rep = 0; rep < 17; rep++) {
        int kk = kq + rep * 4;
        if (kk < 67) {
            int k = k0 - 3 + kk;
            tile[kk][ii] = (k >= 0) ? P[(size_t)k * NG + i0 + ii] : 0.0f;
        }
    }
    __syncthreads();
    int kk2 = t & 63, iq = t >> 6;
    int k = k0 + kk2;
    int c = k % 3, f = k / 3;
    float mm = (c == 0) ? m0 : ((c == 1) ? m1 : m2);
    float rs = rst[f];
    size_t moff = ((size_t)side * NGB + gb) * (size_t)(NG * KF);          // P mat
    size_t voff = ((size_t)(2 + side) * NGB + gb) * (size_t)(NG * KF);    // V mat
    size_t noff = ((size_t)(4 + side) * NGB + gb) * (size_t)(NG * KF);    // NP mat
    float* npP = ws + OFF_NORMP + ((size_t)(side * NGB + gb) * 3 + kt) * NG;
    float* npV = ws + OFF_NORMP + ((size_t)((2 + side) * NGB + gb) * 3 + kt) * NG;
    float* npN = ws + OFF_NORMP + ((size_t)((4 + side) * NGB + gb) * 3 + kt) * NG;
#pragma unroll
    for (int rep = 0; rep < 16; rep++) {
        int i2 = iq + rep * 4;
        float p = tile[kk2 + 3][i2];
        float pm3 = tile[kk2][i2];
        float vV = (k >= 3) ? (p - pm3) : 0.0f;
        float vN = (p - mm) * rs;
        size_t ob = (size_t)(i0 + i2) * KF + k;
        bm[moff + ob] = f2bf(p);
        bm[voff + ob] = f2bf(vV);
        bm[noff + ob] = f2bf(vN);
        float nP = p * p, nV = vV * vV, nN = vN * vN;
#pragma unroll
        for (int off = 32; off; off >>= 1) {
            nP += __shfl_xor(nP, off); nV += __shfl_xor(nV, off); nN += __shfl_xor(nN, off);
        }
        if (kk2 == 0) { npP[i0 + i2] = nP; npV[i0 + i2] = nV; npN[i0 + i2] = nN; }
    }
}

__global__ void k_normfin(float* ws) {
    int mat = blockIdx.x, gb = blockIdx.y;
    const float* np = ws + OFF_NORMP + (size_t)(mat * NGB + gb) * 3 * NG;
    float* nr = ws + OFF_NORMS + ((size_t)mat * NGB + gb) * NG;
    for (int i = threadIdx.x; i < NG; i += 256)
        nr[i] = np[i] + np[NG + i] + np[2 * NG + i];
}

// MFMA distance GEMM: 128x128 tile, 4 waves (2x2), BK=64, swizzled LDS.
// Stores CLAMPED SQUARED distances.
__global__ __launch_bounds__(256) void k_mgemm(float* ws, int cs, unsigned long long dOff) {
    int bx = blockIdx.x, by = blockIdx.y;
    int bz = blockIdx.z; int gbl = bz / 3, m3 = bz % 3;
    int gb = cs + gbl;
    int eIdx = (m3 == 0) ? 0 : ((m3 == 1) ? 4 : 2);
    int aIdx = (m3 == 0) ? 1 : ((m3 == 1) ? 5 : 3);
    const unsigned short* bmat = (const unsigned short*)(ws + OFF_BMAT);
    const unsigned short* Eg = bmat + ((size_t)eIdx * NGB + gb) * (size_t)(NG * KF);
    const unsigned short* Ag = bmat + ((size_t)aIdx * NGB + gb) * (size_t)(NG * KF);
    const float* rnE = ws + OFF_NORMS + ((size_t)eIdx * NGB + gb) * NG;
    const float* cnA = ws + OFF_NORMS + ((size_t)aIdx * NGB + gb) * NG;
    float* D = ws + dOff + ((size_t)gbl * 3 + m3) * (size_t)(NG * NG);
    int i0 = by * 128, j0 = bx * 128;
    __shared__ unsigned short lE[128 * 64];
    __shared__ unsigned short lA[128 * 64];
    int tid = threadIdx.x;
    int wid = tid >> 6, lane = tid & 63;
    int wr = wid >> 1, wc = wid & 1;
    f32x4 acc[4][4];
#pragma unroll
    for (int m = 0; m < 4; m++)
#pragma unroll
        for (int n = 0; n < 4; n++) acc[m][n] = (f32x4){0.f, 0.f, 0.f, 0.f};

    int rr = lane >> 3, ss = lane & 7;
    for (int k0 = 0; k0 < KF; k0 += 64) {
        if (k0) __syncthreads();
#pragma unroll
        for (int q = 0; q < 4; q++) {
            int r0 = wid * 32 + q * 8;
            int r = r0 + rr;
            int c = ss ^ (r & 7);
            __builtin_amdgcn_global_load_lds(
                (const __attribute__((address_space(1))) void*)(Eg + (size_t)(i0 + r) * KF + k0 + c * 8),
                (__attribute__((address_space(3))) void*)&lE[r0 * 64], 16, 0, 0);
            __builtin_amdgcn_global_load_lds(
                (const __attribute__((address_space(1))) void*)(Ag + (size_t)(j0 + r) * KF + k0 + c * 8),
                (__attribute__((address_space(3))) void*)&lA[r0 * 64], 16, 0, 0);
        }
        asm volatile("s_waitcnt vmcnt(0)" ::: "memory");
        __syncthreads();
#pragma unroll
        for (int ks = 0; ks < 2; ks++) {
            bf16x8 af[4], bfr[4];
            int kb = ks * 64 + (lane >> 4) * 16;
#pragma unroll
            for (int m = 0; m < 4; m++) {
                int arow = wr * 64 + m * 16 + (lane & 15);
                af[m] = *(const bf16x8*)((const char*)lE + arow * 128 + (kb ^ ((arow & 7) << 4)));
            }
#pragma unroll
            for (int n = 0; n < 4; n++) {
                int brow = wc * 64 + n * 16 + (lane & 15);
                bfr[n] = *(const bf16x8*)((const char*)lA + brow * 128 + (kb ^ ((brow & 7) << 4)));
            }
#pragma unroll
            for (int m = 0; m < 4; m++)
#pragma unroll
                for (int n = 0; n < 4; n++)
                    acc[m][n] = __builtin_amdgcn_mfma_f32_16x16x32_bf16(af[m], bfr[n], acc[m][n], 0, 0, 0);
        }
    }

    int colbase = j0 + wc * 64 + (lane & 15);
    int rowbase = i0 + wr * 64 + ((lane >> 4) << 2);
    float cn[4];
#pragma unroll
    for (int n = 0; n < 4; n++) cn[n] = cnA[colbase + n * 16];
#pragma unroll
    for (int m = 0; m < 4; m++) {
        int rb = rowbase + m * 16;
#pragma unroll
        for (int r = 0; r < 4; r++) {
            float rn = rnE[rb + r];
#pragma unroll
            for (int n = 0; n < 4; n++) {
                float d = rn + cn[n] - 2.0f * acc[m][n][r];
                D[(size_t)(rb + r) * NG + colbase + n * 16] = fmaxf(d, 1e-12f);
            }
        }
    }
}

// ---- fallback path (small ws): fp32 V/NP derive + norms + fp32 gemm ----
__global__ void k_derive(float* ws) {
    int k = blockIdx.x, gb = blockIdx.y;
    int f = k / 3, c = k % 3;
    for (int side = 0; side < 2; side++) {
        const float* P = ws + OFF_MAT + (size_t)side * MATSZ;
        float* V = ws + OFF_MAT + (size_t)(2 + side) * MATSZ;
        float* NP = ws + OFF_MAT + (size_t)(4 + side) * MATSZ;
        const float* mean = ws + (side ? OFF_MEAN_A : OFF_MEAN_E) + gb * 3;
        const float* rst = ws + (side ? OFF_STD_A : OFF_STD_E) + gb * FF;
        float mm = mean[c];
        float rs = rst[f];
        size_t base = ((size_t)gb * KF + k) * NG;
        for (int i = threadIdx.x; i < NG; i += 256) {
            float p = P[base + i];
            V[base + i] = f ? (p - P[base - 3 * NG + i]) : 0.0f;
            NP[base + i] = (p - mm) * rs;
        }
    }
}

__global__ void k_norms(float* ws) {
    int mat = blockIdx.x, gb = blockIdx.y;
    const float* M = ws + OFF_MAT + (size_t)mat * MATSZ + (size_t)gb * KF * NG;
    float* nr = ws + OFF_NORMS + ((size_t)mat * NGB + gb) * NG;
    for (int i = threadIdx.x; i < NG; i += 256) {
        float s = 0;
        for (int k = 0; k < KF; k++) { float v = M[(size_t)k * NG + i]; s += v * v; }
        nr[i] = s;
    }
}

__global__ __launch_bounds__(256) void k_gemm(float* ws, int cs) {
    int bx = blockIdx.x, by = blockIdx.y;
    int bz = blockIdx.z; int gbl = bz / 3, m = bz % 3;
    int gb = cs + gbl;
    int eIdx = (m == 0) ? 0 : ((m == 1) ? 4 : 2);
    int aIdx = (m == 0) ? 1 : ((m == 1) ? 5 : 3);
    const float* E = ws + OFF_MAT + (size_t)eIdx * MATSZ + (size_t)gb * KF * NG;
    const float* A = ws + OFF_MAT + (size_t)aIdx * MATSZ + (size_t)gb * KF * NG;
    const float* rnE = ws + OFF_NORMS + ((size_t)eIdx * NGB + gb) * NG;
    const float* cnA = ws + OFF_NORMS + ((size_t)aIdx * NGB + gb) * NG;
    float* D = ws + OFF_D + ((size_t)gbl * 3 + m) * (size_t)(NG * NG);
    int i0 = by * 128, j0 = bx * 128;
    __shared__ float4 Et[8][32], At[8][32];
    int tx = threadIdx.x, ty = threadIdx.y;
    int tid = ty * 16 + tx;
    float acc[2][2][4][4] = {};
    for (int k0 = 0; k0 < KF; k0 += 8) {
        {
            int kk = tid >> 5, i4 = tid & 31;
            Et[kk][i4] = *(const float4*)&E[(size_t)(k0 + kk) * NG + i0 + i4 * 4];
            At[kk][i4] = *(const float4*)&A[(size_t)(k0 + kk) * NG + j0 + i4 * 4];
        }
        __syncthreads();
#pragma unroll
        for (int kk = 0; kk < 8; kk++) {
            float4 e0 = Et[kk][ty], e1 = Et[kk][16 + ty];
            float4 a0 = At[kk][tx], a1 = At[kk][16 + tx];
            float er[2][4] = {{e0.x, e0.y, e0.z, e0.w}, {e1.x, e1.y, e1.z, e1.w}};
            float ar[2][4] = {{a0.x, a0.y, a0.z, a0.w}, {a1.x, a1.y, a1.z, a1.w}};
#pragma unroll
            for (int p = 0; p < 2; p++)
#pragma unroll
                for (int q = 0; q < 2; q++)
#pragma unroll
                    for (int r = 0; r < 4; r++)
#pragma unroll
                        for (int cc = 0; cc < 4; cc++)
                            acc[p][q][r][cc] += er[p][r] * ar[q][cc];
        }
        __syncthreads();
    }
    float rn[2][4], cn[2][4];
#pragma unroll
    for (int p = 0; p < 2; p++)
#pragma unroll
        for (int r = 0; r < 4; r++) rn[p][r] = rnE[i0 + p * 64 + ty * 4 + r];
#pragma unroll
    for (int q = 0; q < 2; q++)
#pragma unroll
        for (int cc = 0; cc < 4; cc++) cn[q][cc] = cnA[j0 + q * 64 + tx * 4 + cc];
#pragma unroll
    for (int p = 0; p < 2; p++)
#pragma unroll
        for (int r = 0; r < 4; r++) {
            int gi = i0 + p * 64 + ty * 4 + r;
#pragma unroll
            for (int q = 0; q < 2; q++) {
                float4 o;
                o.x = fmaxf(rn[p][r] + cn[q][0] - 2.0f * acc[p][q][r][0], 1e-12f);
                o.y = fmaxf(rn[p][r] + cn[q][1] - 2.0f * acc[p][q][r][1], 1e-12f);
                o.z = fmaxf(rn[p][r] + cn[q][2] - 2.0f * acc[p][q][r][2], 1e-12f);
                o.w = fmaxf(rn[p][r] + cn[q][3] - 2.0f * acc[p][q][r][3], 1e-12f);
                *(float4*)&D[(size_t)gi * NG + j0 + q * 64 + tx * 4] = o;
            }
        }
}

// per-row top-16 selection on squared distances; sqrt only on selected values
__global__ void k_select(float* ws, int cs, unsigned long long dOff) {
    int gbl = blockIdx.y; int gb = cs + gbl;
    int w = threadIdx.x >> 6, lane = threadIdx.x & 63;
    int row = blockIdx.x * 4 + w;
    const float* Dbase = ws + dOff + (size_t)gbl * 3 * (size_t)(NG * NG);
    const float* dg = Dbase + (size_t)row * NG;
    const float* dn = Dbase + (size_t)(NG * NG) + (size_t)row * NG;
    const float* dv = Dbase + (size_t)2 * (NG * NG) + (size_t)row * NG;
    float dgv[16], dnv[16], dvv[16];
#pragma unroll
    for (int q = 0; q < 16; q++) {
        dgv[q] = dg[q * 64 + lane];
        dnv[q] = dn[q * 64 + lane];
        dvv[q] = dv[q * 64 + lane];
    }
    float sg = 0, sv = 0, sn = 0;
    for (int it = 0; it < KNN; it++) {
        float best = 3.4e38f; int bc = 1 << 30;
#pragma unroll
        for (int q = 0; q < 16; q++) { float v = dgv[q]; int c = q * 64 + lane; if (v < best) { best = v; bc = c; } }
#pragma unroll
        for (int off = 32; off; off >>= 1) {
            float ov = __shfl_xor(best, off); int oc = __shfl_xor(bc, off);
            if (ov < best || (ov == best && oc < bc)) { best = ov; bc = oc; }
        }
        sg += sqrtf(best);
        int bq = bc >> 6, bl = bc & 63;
        float t = 0;
#pragma unroll
        for (int q = 0; q < 16; q++) if (q == bq) t = dvv[q];
        t = __shfl(t, bl); sv += sqrtf(t);
        if (lane == bl) {
#pragma unroll
            for (int q = 0; q < 16; q++) if (q == bq) dgv[q] = 3.4e38f;
        }
    }
    for (int it = 0; it < KNN; it++) {
        float best = 3.4e38f; int bc = 1 << 30;
#pragma unroll
        for (int q = 0; q < 16; q++) { float v = dnv[q]; int c = q * 64 + lane; if (v < best) { best = v; bc = c; } }
#pragma unroll
        for (int off = 32; off; off >>= 1) {
            float ov = __shfl_xor(best, off); int oc = __shfl_xor(bc, off);
            if (ov < best || (ov == best && oc < bc)) { best = ov; bc = oc; }
        }
        sn += sqrtf(best);
        int bq = bc >> 6, bl = bc & 63;
        if (lane == bl) {
#pragma unroll
            for (int q = 0; q < 16; q++) if (q == bq) dnv[q] = 3.4e38f;
        }
    }
    __shared__ float ssum[4][3];
    if (lane == 0) { ssum[w][0] = sg; ssum[w][1] = sn; ssum[w][2] = sv; }
    __syncthreads();
    if (threadIdx.x == 0) {
        float* part = ws + OFF_PART + ((size_t)gb * 256 + blockIdx.x) * 3;
        part[0] = ssum[0][0] + ssum[1][0] + ssum[2][0] + ssum[3][0];
        part[1] = ssum[0][1] + ssum[1][1] + ssum[2][1] + ssum[3][1];
        part[2] = ssum[0][2] + ssum[1][2] + ssum[2][2] + ssum[3][2];
    }
}

__global__ void k_reduce(float* ws, float* out, int n) {
    double s[3] = {0, 0, 0};
    for (int idx = threadIdx.x; idx < n; idx += 256) {
        const float* p = ws + OFF_PART + (size_t)idx * 3;
        s[0] += p[0]; s[1] += p[1]; s[2] += p[2];
    }
    __shared__ double red[256];
    for (int m = 0; m < 3; m++) {
        red[threadIdx.x] = s[m]; __syncthreads();
        for (int off = 128; off; off >>= 1) { if (threadIdx.x < off) red[threadIdx.x] += red[threadIdx.x + off]; __syncthreads(); }
        if (threadIdx.x == 0) out[m] = (float)(red[0] / 524288.0 / 8.0);
        __syncthreads();
    }
}

extern "C" void kernel_launch(void* const* d_in, const int* in_sizes, int n_in,
                              void* d_out, int out_size, void* d_ws, size_t ws_size,
                              hipStream_t stream) {
    const float* ex = (const float*)d_in[0];
    const float* ac = (const float*)d_in[1];
    float* ws = (float*)d_ws;
    float* out = (float*)d_out;

    hipLaunchKernelGGL(k_bg, dim3(32), dim3(256), 0, stream, ex, ac, ws);
    hipLaunchKernelGGL(k_order, dim3(1), dim3(1024), 0, stream, ws);
    hipLaunchKernelGGL(k_gather, dim3(FF, BB, 2), dim3(512), 0, stream, ex, ac, ws);
    hipLaunchKernelGGL(k_meanfin, dim3(NGB, 2), dim3(64), 0, stream, ws);
    hipLaunchKernelGGL(k_std, dim3(FF, NGB, 2), dim3(128), 0, stream, ws);

    size_t ws_floats = ws_size / 4;
    bool fast = ws_floats >= (size_t)FAST_END;

    if (fast) {
        hipLaunchKernelGGL(k_tobf3, dim3(48, NGB, 2), dim3(256), 0, stream, ws);
        hipLaunchKernelGGL(k_normfin, dim3(6, NGB), dim3(256), 0, stream, ws);
        int gbc = 12;  // D overlays the dead fp32 region (6*MATSZ = 12*3*NG*NG)
        for (int cs = 0; cs < NGB; cs += gbc) {
            int take = (NGB - cs < gbc) ? (NGB - cs) : gbc;
            hipLaunchKernelGGL(k_mgemm, dim3(8, 8, take * 3), dim3(256), 0, stream, ws, cs, (unsigned long long)OFF_MAT);
            hipLaunchKernelGGL(k_select, dim3(256, take), dim3(256), 0, stream, ws, cs, (unsigned long long)OFF_MAT);
        }
        hipLaunchKernelGGL(k_reduce, dim3(1), dim3(256), 0, stream, ws, out, 8192);
    } else {
        hipLaunchKernelGGL(k_derive, dim3(KF, NGB), dim3(256), 0, stream, ws);
        hipLaunchKernelGGL(k_norms, dim3(6, NGB), dim3(256), 0, stream, ws);
        size_t dcap = (ws_floats > (size_t)OFF_D) ? (ws_floats - (size_t)OFF_D) : 0;
        int gbc = (int)(dcap / (3ull * NG * NG));
        if (gbc < 1) gbc = 1;
        if (gbc > 32) gbc = 32;
        for (int cs = 0; cs < NGB; cs += gbc) {
            int take = (NGB - cs < gbc) ? (NGB - cs) : gbc;
            hipLaunchKernelGGL(k_gemm, dim3(8, 8, take * 3), dim3(16, 16), 0, stream, ws, cs);
            hipLaunchKernelGGL(k_select, dim3(256, take), dim3(256), 0, stream, ws, cs, (unsigned long long)OFF_D);
        }
        hipLaunchKernelGGL(k_reduce, dim3(1), dim3(256), 0, stream, ws, out, 8192);
    }
}

// Round 7
// 380.278 us; speedup vs baseline: 5.2645x; 1.5268x over previous
//
#include <hip/hip_runtime.h>
#include <math.h>

#define GGRP 8
#define NPTS 8192
#define NG   1024      // points per group
#define BB   4
#define FF   64
#define CH   11
#define KF   192       // feature dim F*3
#define NGB  32        // G*B
#define KNN  16

// ws offsets in FLOATS
#define OFF_ORD_E  0        // 8192 int
#define OFF_ORD_A  8192     // 8192 int
#define OFF_BG_E   16384    // 8192 int
#define OFF_BG_A   24576    // 8192 int
#define OFF_MEAN_E 32768    // 96 f
#define OFF_MEAN_A 32896    // 96 f
#define OFF_STD_E  33024    // 2048 f (stores 1/std)
#define OFF_STD_A  35072    // 2048 f
#define OFF_MEANP  37888    // 2*32*64*3 = 12288 f
#define OFF_PART   50176    // up to 8192*3 f
#define OFF_NORMP  74752    // 6*32*3*1024 = 589824 f
#define OFF_NORMS  664576   // 6*32*1024 = 196608 f
#define OFF_MAT    1048576
#define MATSZ      6291456  // 32*192*1024 floats per matrix-set
#define OFF_BMAT   38797312 // OFF_MAT + 6*MATSZ ; bf16 mats ; D overlays OFF_MAT (12 gb cap)
#define BMAT_FLOATS 18874368
#define FAST_END   57671680 // OFF_BMAT + BMAT_FLOATS
#define OFF_D      38797312 // fallback D region
// logical matrix order: 0 PE, 1 PA, 2 VE, 3 VA, 4 NPE, 5 NPA

typedef short bf16x8 __attribute__((ext_vector_type(8)));
typedef float f32x4 __attribute__((ext_vector_type(4)));

__device__ __forceinline__ unsigned short f2bf(float v) {
    unsigned u = __builtin_bit_cast(unsigned, v);
    return (unsigned short)((u + 0x7fffu + ((u >> 16) & 1u)) >> 16);   // RNE
}

__global__ void k_bg(const float* __restrict__ ex, const float* __restrict__ ac, float* ws) {
    int n = blockIdx.x * blockDim.x + threadIdx.x;
    if (n >= NPTS) return;
    int* bg_e = (int*)ws + OFF_BG_E;
    int* bg_a = (int*)ws + OFF_BG_A;
    const float* pe = ex + (size_t)n * CH + 3;
    const float* pa = ac + (size_t)n * CH + 3;
    float m = -1e30f; int a = 0;
#pragma unroll
    for (int c = 0; c < GGRP; c++) { float v = pe[c]; if (v > m) { m = v; a = c; } }
    bg_e[n] = a;
    m = -1e30f; a = 0;
#pragma unroll
    for (int c = 0; c < GGRP; c++) { float v = pa[c]; if (v > m) { m = v; a = c; } }
    bg_a[n] = a;
}

// stable counting-compaction: 16 waves, wave w<8 -> expected group w, w>=8 -> actual group w-8
__global__ void k_order(float* ws) {
    int tid = threadIdx.x;
    int w = tid >> 6, lane = tid & 63;
    const int* bg = (const int*)ws + ((w < 8) ? OFF_BG_E : OFF_BG_A);
    int* ord = (int*)ws + ((w < 8) ? OFF_ORD_E : OFF_ORD_A);
    int grp = w & 7;
    __shared__ int cnts[16];
    int cnt = 0;
    for (int base = 0; base < NPTS; base += 64) {
        unsigned long long m = __ballot(bg[base + lane] == grp);
        cnt += __popcll(m);
    }
    if (lane == 0) cnts[w] = cnt;
    __syncthreads();
    int pos = 0;
    for (int g2 = 0; g2 < grp; g2++) pos += cnts[(w & 8) | g2];
    for (int base = 0; base < NPTS; base += 64) {
        int hit = (bg[base + lane] == grp);
        unsigned long long m = __ballot(hit);
        int pre = __popcll(m & ((1ull << lane) - 1ull));
        if (hit) { int slot = pos + pre; if (slot < NPTS) ord[slot] = base + lane; }
        pos += __popcll(m);
    }
}

// one block per (f, b, side): full-permutation gather over the whole slab
__global__ __launch_bounds__(512) void k_gather(const float* __restrict__ ex, const float* __restrict__ ac, float* ws) {
    int f = blockIdx.x, b = blockIdx.y, side = blockIdx.z;
    const int* __restrict__ ord = (const int*)ws + (side ? OFF_ORD_A : OFF_ORD_E);
    const float* __restrict__ src = (side ? ac : ex) + ((size_t)(b * FF + f) * NPTS) * CH;
    float* __restrict__ P = ws + OFF_MAT + (size_t)side * MATSZ;
    int t = threadIdx.x;
    int w = t >> 6, lane = t & 63;

    int idxs[16];
#pragma unroll
    for (int it = 0; it < 16; it++) idxs[it] = ord[it * 512 + t];
    float px[16], py[16], pz[16];
#pragma unroll
    for (int it = 0; it < 16; it++) {
        const float* p = src + (size_t)idxs[it] * CH;
        px[it] = p[0]; py[it] = p[1]; pz[it] = p[2];
    }
    __shared__ float accum[8][24];
#pragma unroll
    for (int g = 0; g < 8; g++) {
        float s0 = 0, s1 = 0, s2 = 0;
#pragma unroll
        for (int h = 0; h < 2; h++) {
            int it = g * 2 + h;
            int col = h * 512 + t;
            size_t mb = ((size_t)((g * 4 + b) * KF + f * 3)) * NG + col;
            P[mb] = px[it]; P[mb + NG] = py[it]; P[mb + 2 * NG] = pz[it];
            s0 += px[it]; s1 += py[it]; s2 += pz[it];
        }
#pragma unroll
        for (int off = 32; off; off >>= 1) {
            s0 += __shfl_xor(s0, off); s1 += __shfl_xor(s1, off); s2 += __shfl_xor(s2, off);
        }
        if (lane == 0) { accum[w][g * 3] = s0; accum[w][g * 3 + 1] = s1; accum[w][g * 3 + 2] = s2; }
    }
    __syncthreads();
    if (t < 24) {
        float s = 0;
#pragma unroll
        for (int wv = 0; wv < 8; wv++) s += accum[wv][t];
        int g = t / 3, c = t % 3;
        ws[OFF_MEANP + ((size_t)(side * NGB + (g * 4 + b)) * FF + f) * 3 + c] = s;
    }
}

__global__ void k_meanfin(float* ws) {
    int gb = blockIdx.x, side = blockIdx.y;
    int lane = threadIdx.x;
    const float* mp = ws + OFF_MEANP + ((size_t)(side * NGB + gb) * FF) * 3;
    float s0 = mp[lane * 3], s1 = mp[lane * 3 + 1], s2 = mp[lane * 3 + 2];
#pragma unroll
    for (int off = 32; off; off >>= 1) {
        s0 += __shfl_xor(s0, off); s1 += __shfl_xor(s1, off); s2 += __shfl_xor(s2, off);
    }
    if (lane == 0) {
        float* m = ws + (side ? OFF_MEAN_A : OFF_MEAN_E) + gb * 3;
        m[0] = s0 / 65536.0f; m[1] = s1 / 65536.0f; m[2] = s2 / 65536.0f;
    }
}

// std over (n,3) of centered data, ddof=1 (two-sum form); stores 1/std
__global__ void k_std(float* ws) {
    int f = blockIdx.x, gb = blockIdx.y, side = blockIdx.z;
    int t = threadIdx.x;
    const float* __restrict__ P = ws + OFF_MAT + (size_t)side * MATSZ + ((size_t)gb * KF + f * 3) * NG;
    const float* mean = ws + (side ? OFF_MEAN_A : OFF_MEAN_E) + gb * 3;
    float m0 = mean[0], m1 = mean[1], m2 = mean[2];
    float s1 = 0, s2 = 0;
#pragma unroll
    for (int j = 0; j < 24; j++) {
        int idx = t + j * 128;
        float mm = (j < 8) ? m0 : ((j < 16) ? m1 : m2);
        float v = P[idx] - mm;
        s1 += v; s2 += v * v;
    }
    __shared__ float redA[128], redB[128];
    redA[t] = s1; redB[t] = s2; __syncthreads();
    for (int off = 64; off; off >>= 1) {
        if (t < off) { redA[t] += redA[t + off]; redB[t] += redB[t + off]; }
        __syncthreads();
    }
    if (t == 0) {
        float var = (redB[0] - redA[0] * redA[0] / 3072.0f) / 3071.0f;
        float* st = ws + (side ? OFF_STD_A : OFF_STD_E);
        st[gb * FF + f] = 1.0f / sqrtf(fmaxf(var, 0.0f));
    }
}

// transpose fp32 P [k][i] -> THREE bf16 mats [i][k] (P, V, NP) + norm partials
__global__ void k_tobf3(float* ws) {
    int x = blockIdx.x;
    int it = x & 15, kt = x >> 4;
    int gb = blockIdx.y, side = blockIdx.z;
    const float* __restrict__ P = ws + OFF_MAT + (size_t)side * MATSZ + (size_t)gb * KF * NG;
    unsigned short* bm = (unsigned short*)(ws + OFF_BMAT);
    const float* mean = ws + (side ? OFF_MEAN_A : OFF_MEAN_E) + gb * 3;
    const float* rst = ws + (side ? OFF_STD_A : OFF_STD_E) + gb * FF;
    float m0 = mean[0], m1 = mean[1], m2 = mean[2];
    __shared__ float tile[67][65];   // rows = k0-3 .. k0+63
    int i0 = it * 64, k0 = kt * 64;
    int t = threadIdx.x;
    int ii = t & 63, kq = t >> 6;
#pragma unroll
    for (int rep = 0; rep < 17; rep++) {
        int kk = kq + rep * 4;
        if (kk < 67) {
            int k = k0 - 3 + kk;
            tile[kk][ii] = (k >= 0) ? P[(size_t)k * NG + i0 + ii] : 0.0f;
        }
    }
    __syncthreads();
    int kk2 = t & 63, iq = t >> 6;
    int k = k0 + kk2;
    int c = k % 3, f = k / 3;
    float mm = (c == 0) ? m0 : ((c == 1) ? m1 : m2);
    float rs = rst[f];
    size_t moff = ((size_t)side * NGB + gb) * (size_t)(NG * KF);
    size_t voff = ((size_t)(2 + side) * NGB + gb) * (size_t)(NG * KF);
    size_t noff = ((size_t)(4 + side) * NGB + gb) * (size_t)(NG * KF);
    float* npP = ws + OFF_NORMP + ((size_t)(side * NGB + gb) * 3 + kt) * NG;
    float* npV = ws + OFF_NORMP + ((size_t)((2 + side) * NGB + gb) * 3 + kt) * NG;
    float* npN = ws + OFF_NORMP + ((size_t)((4 + side) * NGB + gb) * 3 + kt) * NG;
#pragma unroll
    for (int rep = 0; rep < 16; rep++) {
        int i2 = iq + rep * 4;
        float p = tile[kk2 + 3][i2];
        float pm3 = tile[kk2][i2];
        float vV = (k >= 3) ? (p - pm3) : 0.0f;
        float vN = (p - mm) * rs;
        size_t ob = (size_t)(i0 + i2) * KF + k;
        bm[moff + ob] = f2bf(p);
        bm[voff + ob] = f2bf(vV);
        bm[noff + ob] = f2bf(vN);
        float nP = p * p, nV = vV * vV, nN = vN * vN;
#pragma unroll
        for (int off = 32; off; off >>= 1) {
            nP += __shfl_xor(nP, off); nV += __shfl_xor(nV, off); nN += __shfl_xor(nN, off);
        }
        if (kk2 == 0) { npP[i0 + i2] = nP; npV[i0 + i2] = nV; npN[i0 + i2] = nN; }
    }
}

__global__ void k_normfin(float* ws) {
    int mat = blockIdx.x, gb = blockIdx.y;
    const float* np = ws + OFF_NORMP + (size_t)(mat * NGB + gb) * 3 * NG;
    float* nr = ws + OFF_NORMS + ((size_t)mat * NGB + gb) * NG;
    for (int i = threadIdx.x; i < NG; i += 256)
        nr[i] = np[i] + np[NG + i] + np[2 * NG + i];
}

// MFMA distance GEMM: 128x128 tile, 4 waves (2x2), BK=64, swizzled LDS.
// Stores CLAMPED SQUARED distances.
__global__ __launch_bounds__(256) void k_mgemm(float* ws, int cs, unsigned long long dOff) {
    int bx = blockIdx.x, by = blockIdx.y;
    int bz = blockIdx.z; int gbl = bz / 3, m3 = bz % 3;
    int gb = cs + gbl;
    int eIdx = (m3 == 0) ? 0 : ((m3 == 1) ? 4 : 2);
    int aIdx = (m3 == 0) ? 1 : ((m3 == 1) ? 5 : 3);
    const unsigned short* bmat = (const unsigned short*)(ws + OFF_BMAT);
    const unsigned short* Eg = bmat + ((size_t)eIdx * NGB + gb) * (size_t)(NG * KF);
    const unsigned short* Ag = bmat + ((size_t)aIdx * NGB + gb) * (size_t)(NG * KF);
    const float* rnE = ws + OFF_NORMS + ((size_t)eIdx * NGB + gb) * NG;
    const float* cnA = ws + OFF_NORMS + ((size_t)aIdx * NGB + gb) * NG;
    float* D = ws + dOff + ((size_t)gbl * 3 + m3) * (size_t)(NG * NG);
    int i0 = by * 128, j0 = bx * 128;
    __shared__ unsigned short lE[128 * 64];
    __shared__ unsigned short lA[128 * 64];
    int tid = threadIdx.x;
    int wid = tid >> 6, lane = tid & 63;
    int wr = wid >> 1, wc = wid & 1;
    f32x4 acc[4][4];
#pragma unroll
    for (int m = 0; m < 4; m++)
#pragma unroll
        for (int n = 0; n < 4; n++) acc[m][n] = (f32x4){0.f, 0.f, 0.f, 0.f};

    int rr = lane >> 3, ss = lane & 7;
    for (int k0 = 0; k0 < KF; k0 += 64) {
        if (k0) __syncthreads();
#pragma unroll
        for (int q = 0; q < 4; q++) {
            int r0 = wid * 32 + q * 8;
            int r = r0 + rr;
            int c = ss ^ (r & 7);
            __builtin_amdgcn_global_load_lds(
                (const __attribute__((address_space(1))) void*)(Eg + (size_t)(i0 + r) * KF + k0 + c * 8),
                (__attribute__((address_space(3))) void*)&lE[r0 * 64], 16, 0, 0);
            __builtin_amdgcn_global_load_lds(
                (const __attribute__((address_space(1))) void*)(Ag + (size_t)(j0 + r) * KF + k0 + c * 8),
                (__attribute__((address_space(3))) void*)&lA[r0 * 64], 16, 0, 0);
        }
        asm volatile("s_waitcnt vmcnt(0)" ::: "memory");
        __syncthreads();
#pragma unroll
        for (int ks = 0; ks < 2; ks++) {
            bf16x8 af[4], bfr[4];
            int kb = ks * 64 + (lane >> 4) * 16;
#pragma unroll
            for (int m = 0; m < 4; m++) {
                int arow = wr * 64 + m * 16 + (lane & 15);
                af[m] = *(const bf16x8*)((const char*)lE + arow * 128 + (kb ^ ((arow & 7) << 4)));
            }
#pragma unroll
            for (int n = 0; n < 4; n++) {
                int brow = wc * 64 + n * 16 + (lane & 15);
                bfr[n] = *(const bf16x8*)((const char*)lA + brow * 128 + (kb ^ ((brow & 7) << 4)));
            }
#pragma unroll
            for (int m = 0; m < 4; m++)
#pragma unroll
                for (int n = 0; n < 4; n++)
                    acc[m][n] = __builtin_amdgcn_mfma_f32_16x16x32_bf16(af[m], bfr[n], acc[m][n], 0, 0, 0);
        }
    }

    int colbase = j0 + wc * 64 + (lane & 15);
    int rowbase = i0 + wr * 64 + ((lane >> 4) << 2);
    float cn[4];
#pragma unroll
    for (int n = 0; n < 4; n++) cn[n] = cnA[colbase + n * 16];
#pragma unroll
    for (int m = 0; m < 4; m++) {
        int rb = rowbase + m * 16;
#pragma unroll
        for (int r = 0; r < 4; r++) {
            float rn = rnE[rb + r];
#pragma unroll
            for (int n = 0; n < 4; n++) {
                float d = rn + cn[n] - 2.0f * acc[m][n][r];
                D[(size_t)(rb + r) * NG + colbase + n * 16] = fmaxf(d, 1e-12f);
            }
        }
    }
}

// ---- fallback path (small ws): fp32 V/NP derive + norms + fp32 gemm ----
__global__ void k_derive(float* ws) {
    int k = blockIdx.x, gb = blockIdx.y;
    int f = k / 3, c = k % 3;
    for (int side = 0; side < 2; side++) {
        const float* P = ws + OFF_MAT + (size_t)side * MATSZ;
        float* V = ws + OFF_MAT + (size_t)(2 + side) * MATSZ;
        float* NP = ws + OFF_MAT + (size_t)(4 + side) * MATSZ;
        const float* mean = ws + (side ? OFF_MEAN_A : OFF_MEAN_E) + gb * 3;
        const float* rst = ws + (side ? OFF_STD_A : OFF_STD_E) + gb * FF;
        float mm = mean[c];
        float rs = rst[f];
        size_t base = ((size_t)gb * KF + k) * NG;
        for (int i = threadIdx.x; i < NG; i += 256) {
            float p = P[base + i];
            V[base + i] = f ? (p - P[base - 3 * NG + i]) : 0.0f;
            NP[base + i] = (p - mm) * rs;
        }
    }
}

__global__ void k_norms(float* ws) {
    int mat = blockIdx.x, gb = blockIdx.y;
    const float* M = ws + OFF_MAT + (size_t)mat * MATSZ + (size_t)gb * KF * NG;
    float* nr = ws + OFF_NORMS + ((size_t)mat * NGB + gb) * NG;
    for (int i = threadIdx.x; i < NG; i += 256) {
        float s = 0;
        for (int k = 0; k < KF; k++) { float v = M[(size_t)k * NG + i]; s += v * v; }
        nr[i] = s;
    }
}

__global__ __launch_bounds__(256) void k_gemm(float* ws, int cs) {
    int bx = blockIdx.x, by = blockIdx.y;
    int bz = blockIdx.z; int gbl = bz / 3, m = bz % 3;
    int gb = cs + gbl;
    int eIdx = (m == 0) ? 0 : ((m == 1) ? 4 : 2);
    int aIdx = (m == 0) ? 1 : ((m == 1) ? 5 : 3);
    const float* E = ws + OFF_MAT + (size_t)eIdx * MATSZ + (size_t)gb * KF * NG;
    const float* A = ws + OFF_MAT + (size_t)aIdx * MATSZ + (size_t)gb * KF * NG;
    const float* rnE = ws + OFF_NORMS + ((size_t)eIdx * NGB + gb) * NG;
    const float* cnA = ws + OFF_NORMS + ((size_t)aIdx * NGB + gb) * NG;
    float* D = ws + OFF_D + ((size_t)gbl * 3 + m) * (size_t)(NG * NG);
    int i0 = by * 128, j0 = bx * 128;
    __shared__ float4 Et[8][32], At[8][32];
    int tx = threadIdx.x, ty = threadIdx.y;
    int tid = ty * 16 + tx;
    float acc[2][2][4][4] = {};
    for (int k0 = 0; k0 < KF; k0 += 8) {
        {
            int kk = tid >> 5, i4 = tid & 31;
            Et[kk][i4] = *(const float4*)&E[(size_t)(k0 + kk) * NG + i0 + i4 * 4];
            At[kk][i4] = *(const float4*)&A[(size_t)(k0 + kk) * NG + j0 + i4 * 4];
        }
        __syncthreads();
#pragma unroll
        for (int kk = 0; kk < 8; kk++) {
            float4 e0 = Et[kk][ty], e1 = Et[kk][16 + ty];
            float4 a0 = At[kk][tx], a1 = At[kk][16 + tx];
            float er[2][4] = {{e0.x, e0.y, e0.z, e0.w}, {e1.x, e1.y, e1.z, e1.w}};
            float ar[2][4] = {{a0.x, a0.y, a0.z, a0.w}, {a1.x, a1.y, a1.z, a1.w}};
#pragma unroll
            for (int p = 0; p < 2; p++)
#pragma unroll
                for (int q = 0; q < 2; q++)
#pragma unroll
                    for (int r = 0; r < 4; r++)
#pragma unroll
                        for (int cc = 0; cc < 4; cc++)
                            acc[p][q][r][cc] += er[p][r] * ar[q][cc];
        }
        __syncthreads();
    }
    float rn[2][4], cn[2][4];
#pragma unroll
    for (int p = 0; p < 2; p++)
#pragma unroll
        for (int r = 0; r < 4; r++) rn[p][r] = rnE[i0 + p * 64 + ty * 4 + r];
#pragma unroll
    for (int q = 0; q < 2; q++)
#pragma unroll
        for (int cc = 0; cc < 4; cc++) cn[q][cc] = cnA[j0 + q * 64 + tx * 4 + cc];
#pragma unroll
    for (int p = 0; p < 2; p++)
#pragma unroll
        for (int r = 0; r < 4; r++) {
            int gi = i0 + p * 64 + ty * 4 + r;
#pragma unroll
            for (int q = 0; q < 2; q++) {
                float4 o;
                o.x = fmaxf(rn[p][r] + cn[q][0] - 2.0f * acc[p][q][r][0], 1e-12f);
                o.y = fmaxf(rn[p][r] + cn[q][1] - 2.0f * acc[p][q][r][1], 1e-12f);
                o.z = fmaxf(rn[p][r] + cn[q][2] - 2.0f * acc[p][q][r][2], 1e-12f);
                o.w = fmaxf(rn[p][r] + cn[q][3] - 2.0f * acc[p][q][r][3], 1e-12f);
                *(float4*)&D[(size_t)gi * NG + j0 + q * 64 + tx * 4] = o;
            }
        }
}

// ---------------------------------------------------------------------------
// per-row top-16 on squared distances via bound -> compact -> bitonic sort.
// tau = 16th-smallest of the 64 per-lane minima  =>  {v<=tau} superset of the
// stable top-16 (the 16 lanes with smallest minima give 16 elements <= tau).
// Compact candidates (E[#]=18) into per-wave LDS slots, 64-lane bitonic sort
// by (value, col), lanes 0..15 = exact stable top-16. Fallback to the serial
// extraction loop if count > 64 (degenerate ties).
// ---------------------------------------------------------------------------
__global__ void k_select(float* ws, int cs, unsigned long long dOff) {
    int gbl = blockIdx.y; int gb = cs + gbl;
    int w = threadIdx.x >> 6, lane = threadIdx.x & 63;
    int row = blockIdx.x * 4 + w;
    const float* Dbase = ws + dOff + (size_t)gbl * 3 * (size_t)(NG * NG);
    const float* dg = Dbase + (size_t)row * NG;
    const float* dn = Dbase + (size_t)(NG * NG) + (size_t)row * NG;
    const float* dv = Dbase + (size_t)2 * (NG * NG) + (size_t)row * NG;
    float dgv[16], dnv[16], dvv[16];
#pragma unroll
    for (int q = 0; q < 16; q++) {
        dgv[q] = dg[q * 64 + lane];
        dnv[q] = dn[q * 64 + lane];
        dvv[q] = dv[q * 64 + lane];
    }
    __shared__ float sKey[4][64];
    __shared__ float sPay[4][64];
    __shared__ int   sCol[4][64];
    unsigned long long ltm = (1ull << lane) - 1ull;
    float sg = 0, sv = 0, sn = 0;

    // ============ list A: dg (payload dv, tie-break col) ============
    {
        float lm = dgv[0];
#pragma unroll
        for (int q = 1; q < 16; q++) lm = fminf(lm, dgv[q]);
        // bitonic sort of 64 lane-minima (values only, ascending)
#pragma unroll
        for (int k2 = 2; k2 <= 64; k2 <<= 1)
#pragma unroll
            for (int j = k2 >> 1; j; j >>= 1) {
                float o = __shfl_xor(lm, j);
                bool takeMin = (((lane & j) == 0) == ((lane & k2) == 0));
                lm = takeMin ? fminf(lm, o) : fmaxf(lm, o);
            }
        float tau = __shfl(lm, 15);
        int cnt = 0;
#pragma unroll
        for (int q = 0; q < 16; q++) cnt += (int)__popcll(__ballot(dgv[q] <= tau));
        if (cnt <= 64) {
            int base = 0;
#pragma unroll
            for (int q = 0; q < 16; q++) {
                bool c = (dgv[q] <= tau);
                unsigned long long bal = __ballot(c);
                if (c) {
                    int slot = base + (int)__popcll(bal & ltm);
                    sKey[w][slot] = dgv[q]; sPay[w][slot] = dvv[q]; sCol[w][slot] = q * 64 + lane;
                }
                base += (int)__popcll(bal);
            }
            asm volatile("s_waitcnt lgkmcnt(0)" ::: "memory");
            float key = (lane < cnt) ? sKey[w][lane] : 3.4e38f;
            float pay = (lane < cnt) ? sPay[w][lane] : 0.0f;
            int   col = (lane < cnt) ? sCol[w][lane] : 0x7fffffff;
#pragma unroll
            for (int k2 = 2; k2 <= 64; k2 <<= 1)
#pragma unroll
                for (int j = k2 >> 1; j; j >>= 1) {
                    float ok = __shfl_xor(key, j);
                    float op = __shfl_xor(pay, j);
                    int   oc = __shfl_xor(col, j);
                    bool mineSmaller = (key < ok) || (key == ok && col < oc);
                    bool wantSmall = (((lane & j) == 0) == ((lane & k2) == 0));
                    if (mineSmaller != wantSmall) { key = ok; pay = op; col = oc; }
                }
            float a = (lane < 16) ? sqrtf(key) : 0.0f;
            float b = (lane < 16) ? sqrtf(pay) : 0.0f;
#pragma unroll
            for (int off = 32; off; off >>= 1) { a += __shfl_xor(a, off); b += __shfl_xor(b, off); }
            sg = a; sv = b;
        } else {
            // fallback: serial 16-round extraction (exact)
            for (int it = 0; it < KNN; it++) {
                float best = 3.4e38f; int bc = 1 << 30;
#pragma unroll
                for (int q = 0; q < 16; q++) { float v = dgv[q]; int c = q * 64 + lane; if (v < best) { best = v; bc = c; } }
#pragma unroll
                for (int off = 32; off; off >>= 1) {
                    float ov = __shfl_xor(best, off); int oc = __shfl_xor(bc, off);
                    if (ov < best || (ov == best && oc < bc)) { best = ov; bc = oc; }
                }
                sg += sqrtf(best);
                int bq = bc >> 6, bl = bc & 63;
                float t = 0;
#pragma unroll
                for (int q = 0; q < 16; q++) if (q == bq) t = dvv[q];
                t = __shfl(t, bl); sv += sqrtf(t);
                if (lane == bl) {
#pragma unroll
                    for (int q = 0; q < 16; q++) if (q == bq) dgv[q] = 3.4e38f;
                }
            }
        }
    }

    // ============ list B: dn (values only) ============
    {
        float lm = dnv[0];
#pragma unroll
        for (int q = 1; q < 16; q++) lm = fminf(lm, dnv[q]);
#pragma unroll
        for (int k2 = 2; k2 <= 64; k2 <<= 1)
#pragma unroll
            for (int j = k2 >> 1; j; j >>= 1) {
                float o = __shfl_xor(lm, j);
                bool takeMin = (((lane & j) == 0) == ((lane & k2) == 0));
                lm = takeMin ? fminf(lm, o) : fmaxf(lm, o);
            }
        float tau = __shfl(lm, 15);
        int cnt = 0;
#pragma unroll
        for (int q = 0; q < 16; q++) cnt += (int)__popcll(__ballot(dnv[q] <= tau));
        if (cnt <= 64) {
            int base = 0;
#pragma unroll
            for (int q = 0; q < 16; q++) {
                bool c = (dnv[q] <= tau);
                unsigned long long bal = __ballot(c);
                if (c) {
                    int slot = base + (int)__popcll(bal & ltm);
                    sKey[w][slot] = dnv[q];
                }
                base += (int)__popcll(bal);
            }
            asm volatile("s_waitcnt lgkmcnt(0)" ::: "memory");
            float key = (lane < cnt) ? sKey[w][lane] : 3.4e38f;
#pragma unroll
            for (int k2 = 2; k2 <= 64; k2 <<= 1)
#pragma unroll
                for (int j = k2 >> 1; j; j >>= 1) {
                    float o = __shfl_xor(key, j);
                    bool takeMin = (((lane & j) == 0) == ((lane & k2) == 0));
                    key = takeMin ? fminf(key, o) : fmaxf(key, o);
                }
            float a = (lane < 16) ? sqrtf(key) : 0.0f;
#pragma unroll
            for (int off = 32; off; off >>= 1) a += __shfl_xor(a, off);
            sn = a;
        } else {
            for (int it = 0; it < KNN; it++) {
                float best = 3.4e38f; int bc = 1 << 30;
#pragma unroll
                for (int q = 0; q < 16; q++) { float v = dnv[q]; int c = q * 64 + lane; if (v < best) { best = v; bc = c; } }
#pragma unroll
                for (int off = 32; off; off >>= 1) {
                    float ov = __shfl_xor(best, off); int oc = __shfl_xor(bc, off);
                    if (ov < best || (ov == best && oc < bc)) { best = ov; bc = oc; }
                }
                sn += sqrtf(best);
                int bq = bc >> 6, bl = bc & 63;
                if (lane == bl) {
#pragma unroll
                    for (int q = 0; q < 16; q++) if (q == bq) dnv[q] = 3.4e38f;
                }
            }
        }
    }

    __shared__ float ssum[4][3];
    if (lane == 0) { ssum[w][0] = sg; ssum[w][1] = sn; ssum[w][2] = sv; }
    __syncthreads();
    if (threadIdx.x == 0) {
        float* part = ws + OFF_PART + ((size_t)gb * 256 + blockIdx.x) * 3;
        part[0] = ssum[0][0] + ssum[1][0] + ssum[2][0] + ssum[3][0];
        part[1] = ssum[0][1] + ssum[1][1] + ssum[2][1] + ssum[3][1];
        part[2] = ssum[0][2] + ssum[1][2] + ssum[2][2] + ssum[3][2];
    }
}

__global__ void k_reduce(float* ws, float* out, int n) {
    double s[3] = {0, 0, 0};
    for (int idx = threadIdx.x; idx < n; idx += 256) {
        const float* p = ws + OFF_PART + (size_t)idx * 3;
        s[0] += p[0]; s[1] += p[1]; s[2] += p[2];
    }
    __shared__ double red[256];
    for (int m = 0; m < 3; m++) {
        red[threadIdx.x] = s[m]; __syncthreads();
        for (int off = 128; off; off >>= 1) { if (threadIdx.x < off) red[threadIdx.x] += red[threadIdx.x + off]; __syncthreads(); }
        if (threadIdx.x == 0) out[m] = (float)(red[0] / 524288.0 / 8.0);
        __syncthreads();
    }
}

extern "C" void kernel_launch(void* const* d_in, const int* in_sizes, int n_in,
                              void* d_out, int out_size, void* d_ws, size_t ws_size,
                              hipStream_t stream) {
    const float* ex = (const float*)d_in[0];
    const float* ac = (const float*)d_in[1];
    float* ws = (float*)d_ws;
    float* out = (float*)d_out;

    hipLaunchKernelGGL(k_bg, dim3(32), dim3(256), 0, stream, ex, ac, ws);
    hipLaunchKernelGGL(k_order, dim3(1), dim3(1024), 0, stream, ws);
    hipLaunchKernelGGL(k_gather, dim3(FF, BB, 2), dim3(512), 0, stream, ex, ac, ws);
    hipLaunchKernelGGL(k_meanfin, dim3(NGB, 2), dim3(64), 0, stream, ws);
    hipLaunchKernelGGL(k_std, dim3(FF, NGB, 2), dim3(128), 0, stream, ws);

    size_t ws_floats = ws_size / 4;
    bool fast = ws_floats >= (size_t)FAST_END;

    if (fast) {
        hipLaunchKernelGGL(k_tobf3, dim3(48, NGB, 2), dim3(256), 0, stream, ws);
        hipLaunchKernelGGL(k_normfin, dim3(6, NGB), dim3(256), 0, stream, ws);
        int gbc = 12;  // D overlays the dead fp32 region (6*MATSZ = 12*3*NG*NG)
        for (int cs = 0; cs < NGB; cs += gbc) {
            int take = (NGB - cs < gbc) ? (NGB - cs) : gbc;
            hipLaunchKernelGGL(k_mgemm, dim3(8, 8, take * 3), dim3(256), 0, stream, ws, cs, (unsigned long long)OFF_MAT);
            hipLaunchKernelGGL(k_select, dim3(256, take), dim3(256), 0, stream, ws, cs, (unsigned long long)OFF_MAT);
        }
        hipLaunchKernelGGL(k_reduce, dim3(1), dim3(256), 0, stream, ws, out, 8192);
    } else {
        hipLaunchKernelGGL(k_derive, dim3(KF, NGB), dim3(256), 0, stream, ws);
        hipLaunchKernelGGL(k_norms, dim3(6, NGB), dim3(256), 0, stream, ws);
        size_t dcap = (ws_floats > (size_t)OFF_D) ? (ws_floats - (size_t)OFF_D) : 0;
        int gbc = (int)(dcap / (3ull * NG * NG));
        if (gbc < 1) gbc = 1;
        if (gbc > 32) gbc = 32;
        for (int cs = 0; cs < NGB; cs += gbc) {
            int take = (NGB - cs < gbc) ? (NGB - cs) : gbc;
            hipLaunchKernelGGL(k_gemm, dim3(8, 8, take * 3), dim3(16, 16), 0, stream, ws, cs);
            hipLaunchKernelGGL(k_select, dim3(256, take), dim3(256), 0, stream, ws, cs, (unsigned long long)OFF_D);
        }
        hipLaunchKernelGGL(k_reduce, dim3(1), dim3(256), 0, stream, ws, out, 8192);
    }
}